// Round 1
// baseline (202.180 us; speedup 1.0000x reference)
//
#include <hip/hip_runtime.h>
#include <hip/hip_bf16.h>

#define BB 16
#define NN 1024
#define DD 5
#define RH 8

typedef unsigned long long u64;
typedef unsigned int u32;
typedef __hip_bfloat16 bf16;

static __device__ __forceinline__ float tof(bf16 x) { return __bfloat162float(x); }
// runtime-dtype load: f32 storage if f==true else bf16
static __device__ __forceinline__ float ldf(const void* p, long long i, bool f) {
  return f ? ((const float*)p)[i] : tof(((const bf16*)p)[i]);
}

#define LOG2E 1.4426950408889634f
#define PACK_BLOCKS (BB * NN * 16 / 256)  // 1024
#define KV_BLOCKS (BB * NN / 256)         // 64

// Round 13: collapse 4 dispatches -> 2.
//  Theory: per-kernel roofline work sums to ~40us but measured kernel time is
//  ~147us -> the residual is dispatch-boundary serialization + the 16-block
//  latency-bound k_final. Restructure k_attn to one block per (b, 16-row
//  chunk) over the FULL j range (grid BB*64):
//   - two-hop mask built in-block from adjbits (no redundancy: each row owned
//     by exactly one block -- fixes r14's failure mode). neighbits buffer gone.
//   - softmax denominator complete in-block -> pool via 5 device-scope
//     atomicAdd per block + last-block-per-b runs the tiny MLP (fixes r9/r15
//     failure modes: no all-thread fences, atomics only on 5 floats/block).
//  Carried-over lessons: no min-waves __launch_bounds__, no it-loop unroll
//  pragma, exp2 with folded log2e, collapsed radial MLP, dtype probe.

// ---------------------------------------------------------------- pack + kv
__global__ __launch_bounds__(256) void k_pack(
    const void* __restrict__ adj, const void* __restrict__ feats,
    const void* __restrict__ coors,
    const void* __restrict__ Wk, const void* __restrict__ Wv,
    const void* __restrict__ Wo,
    u64* __restrict__ adjbits, float4* __restrict__ kvg,
    float* __restrict__ czg, int* __restrict__ gflags,
    float* __restrict__ pooled, int* __restrict__ cntr) {
  __shared__ int sNon01, sNonpair, sLow3;
  __shared__ int sCnt[4];
  __shared__ float wkL[25], wvL[25], woL[25];
  int tid = threadIdx.x;

  if (blockIdx.x >= PACK_BLOCKS) {
    // ---------------- kv precompute role ----------------
    int kb = blockIdx.x - PACK_BLOCKS;
    if (kb == 0) {
      // zero the pooled accumulators + block counters for this iteration
      // (workspace is poisoned between iterations). Plain stores; kernel-end
      // flush makes them visible to k_attn's atomics (same mechanism as
      // adjbits/gflags today).
      if (tid < BB * DD) pooled[tid] = 0.0f;
      else if (tid < BB * DD + BB) cntr[tid - BB * DD] = 0;
    }
    {
      u32 x = ((const u32*)feats)[tid];
      u32 lo = x & 0xFFFFu;
      int e = (int)((lo >> 7) & 0xFFu);
      bool insane = !(lo == 0u || (e >= 90 && e <= 150));
      u64 m = __ballot(insane);
      if ((tid & 63) == 0) sCnt[tid >> 6] = (int)__popcll(m);
    }
    __syncthreads();
    bool f32 = (sCnt[0] + sCnt[1] + sCnt[2] + sCnt[3]) > 64;
    if (tid < 25) {
      wkL[tid] = ldf(Wk, tid, f32);
      wvL[tid] = ldf(Wv, tid, f32);
      woL[tid] = ldf(Wo, tid, f32);
    }
    if (kb == 0 && tid == 0) gflags[0] = f32 ? 1 : 0;
    __syncthreads();
    long long node = (long long)kb * 256 + tid;  // < BB*NN
    float f0 = ldf(feats, node * DD + 0, f32), f1 = ldf(feats, node * DD + 1, f32),
          f2 = ldf(feats, node * DD + 2, f32), f3 = ldf(feats, node * DD + 3, f32),
          f4 = ldf(feats, node * DD + 4, f32);
    float k[DD], tv[DD], v[DD];
    #pragma unroll
    for (int e = 0; e < DD; ++e) {
      k[e] = f0 * wkL[e] + f1 * wkL[5 + e] + f2 * wkL[10 + e] + f3 * wkL[15 + e] +
             f4 * wkL[20 + e];
      tv[e] = f0 * wvL[e] + f1 * wvL[5 + e] + f2 * wvL[10 + e] + f3 * wvL[15 + e] +
              f4 * wvL[20 + e];
    }
    #pragma unroll
    for (int e = 0; e < DD; ++e)
      v[e] = tv[0] * woL[e] + tv[1] * woL[5 + e] + tv[2] * woL[10 + e] +
             tv[3] * woL[15 + e] + tv[4] * woL[20 + e];
    float cx = ldf(coors, node * 3 + 0, f32);
    float cy = ldf(coors, node * 3 + 1, f32);
    float cz = ldf(coors, node * 3 + 2, f32);
    kvg[node * 3 + 0] = make_float4(k[0], k[1], k[2], k[3]);
    kvg[node * 3 + 1] = make_float4(k[4], v[0], v[1], v[2]);
    kvg[node * 3 + 2] = make_float4(v[3], v[4], cx, cy);
    czg[node] = cz;
    return;
  }

  // ---------------- adjacency pack role ----------------
  if (tid == 0) { sNon01 = 0; sNonpair = 0; sLow3 = 0; }
  __syncthreads();
  {
    const u32* aw = (const u32*)adj;
    int non01 = 0, nonpair = 0, low3 = 0;
    for (int i = tid; i < 4096; i += 256) {
      u32 x = aw[i];
      u32 lo = x & 0xFFFFu, hi = x >> 16;
      non01 |= (x > 1u);
      nonpair |= !((lo == 0u || lo == 0x3F80u) && (hi == 0u || hi == 0x3F80u));
      low3 |= (lo == 0x3F80u);
    }
    if (non01) atomicOr(&sNon01, 1);
    if (nonpair) atomicOr(&sNonpair, 1);
    if (low3) atomicOr(&sLow3, 1);
  }
  __syncthreads();
  // mode: 0=int32, 1=byte, 2=bf16, 3=f32
  int mode;
  if (!sNon01) mode = 0;
  else if (!sNonpair) mode = sLow3 ? 2 : 3;
  else mode = 1;

  int gid = blockIdx.x * 256 + tid;
  int w = gid & 15;
  long long row = gid >> 4;
  long long base = row * NN + (long long)w * 64;
  u64 bits = 0;
  if (mode == 3) {
    const uint4* p = (const uint4*)((const float*)adj + base);
    #pragma unroll
    for (int t = 0; t < 16; ++t) {
      uint4 x = p[t];
      if (x.x << 1) bits |= 1ull << (4 * t + 0);   // ignore -0.0
      if (x.y << 1) bits |= 1ull << (4 * t + 1);
      if (x.z << 1) bits |= 1ull << (4 * t + 2);
      if (x.w << 1) bits |= 1ull << (4 * t + 3);
    }
  } else if (mode == 0) {
    const uint4* p = (const uint4*)((const u32*)adj + base);
    #pragma unroll
    for (int t = 0; t < 16; ++t) {
      uint4 x = p[t];
      if (x.x) bits |= 1ull << (4 * t + 0);
      if (x.y) bits |= 1ull << (4 * t + 1);
      if (x.z) bits |= 1ull << (4 * t + 2);
      if (x.w) bits |= 1ull << (4 * t + 3);
    }
  } else if (mode == 2) {
    const uint4* p = (const uint4*)((const unsigned short*)adj + base);
    #pragma unroll
    for (int t = 0; t < 8; ++t) {
      uint4 x = p[t];
      u32 c[4] = {x.x, x.y, x.z, x.w};
      #pragma unroll
      for (int q = 0; q < 4; ++q) {
        if ((c[q] & 0x7FFFu)) bits |= 1ull << (8 * t + 2 * q + 0);
        if ((c[q] >> 16) & 0x7FFFu) bits |= 1ull << (8 * t + 2 * q + 1);
      }
    }
  } else {
    const uint4* p = (const uint4*)((const unsigned char*)adj + base);
    #pragma unroll
    for (int t = 0; t < 4; ++t) {
      uint4 x = p[t];
      u32 c[4] = {x.x, x.y, x.z, x.w};
      #pragma unroll
      for (int q = 0; q < 4; ++q)
        #pragma unroll
        for (int bb = 0; bb < 4; ++bb)
          if ((c[q] >> (8 * bb)) & 0xFFu) bits |= 1ull << (16 * t + 4 * q + bb);
    }
  }
  adjbits[gid] = bits;
}

// ---------------- fused: two-hop + attention + pool + last-block MLP
__global__ __launch_bounds__(256) void k_attn(
    const void* __restrict__ feats, const void* __restrict__ coors,
    const void* __restrict__ Wq,
    const void* __restrict__ wr1, const void* __restrict__ br1,
    const void* __restrict__ wr2, const void* __restrict__ br2,
    const float4* __restrict__ kvg, const float* __restrict__ czg,
    const int* __restrict__ gflags, const u64* __restrict__ adjbits,
    float* __restrict__ pooled, int* __restrict__ cntr,
    const void* __restrict__ w1, const void* __restrict__ b1,
    const void* __restrict__ w2, const void* __restrict__ b2,
    float* __restrict__ out) {
  __shared__ __align__(16) float4 kvL[NN * 3];        // 48 KB
  __shared__ float czL[NN];                           // 4 KB
  __shared__ unsigned short listL[4][NN];             // 8 KB (reused post-twohop)
  __shared__ u64 neighL[16][16];                      // 2 KB
  __shared__ float qL[16 * DD], ciL[16 * 3];
  __shared__ float wqL[25];
  __shared__ float wrL[3][RH];
  __shared__ float sConst[2];
  __shared__ int sFast, sLast;

  int bi = blockIdx.x;
  int b = bi >> 6, chunk = bi & 63;   // 64 chunks of 16 rows, full j range
  int tid = threadIdx.x;
  bool f32 = gflags[0] != 0;
  if (tid < 25) wqL[tid] = ldf(Wq, tid, f32);
  if (tid >= 64 && tid < 64 + RH) {
    int h = tid - 64;
    wrL[0][h] = ldf(wr1, h, f32);
    wrL[1][h] = ldf(br1, h, f32);
    wrL[2][h] = ldf(wr2, h, f32);
  }
  if (tid == 96) {
    float c = 0.0f;
    int ok = 1;
    #pragma unroll
    for (int h = 0; h < RH; ++h) {
      float w1h = ldf(wr1, h, f32);
      if (ldf(br1, h, f32) != 0.0f) ok = 0;
      if (w1h > 0.0f) c += w1h * ldf(wr2, h, f32);
    }
    sConst[0] = c * LOG2E;
    sConst[1] = ldf(br2, 0, f32) * LOG2E;
    sFast = ok;
  }
  // stage full-batch kv records + cz: pure coalesced copy (L2-resident source)
  {
    const float4* src = kvg + (size_t)b * NN * 3;
    for (int idx = tid; idx < NN * 3; idx += 256) kvL[idx] = src[idx];
    const float* csrc = czg + (size_t)b * NN;
    for (int idx = tid; idx < NN; idx += 256) czL[idx] = csrc[idx];
  }
  __syncthreads();
  int fast = sFast;
  // q (scaled) + ci for this chunk's 16 rows
  if (tid < 16) {
    long long row = (long long)b * NN + chunk * 16 + tid;
    float f0 = ldf(feats, row * DD + 0, f32), f1 = ldf(feats, row * DD + 1, f32),
          f2 = ldf(feats, row * DD + 2, f32), f3 = ldf(feats, row * DD + 3, f32),
          f4 = ldf(feats, row * DD + 4, f32);
    float qsc = fast ? (0.4472135954999579f * LOG2E) : 0.4472135954999579f;
    #pragma unroll
    for (int e = 0; e < DD; ++e)
      qL[tid * DD + e] = (f0 * wqL[e] + f1 * wqL[5 + e] + f2 * wqL[10 + e] +
                          f3 * wqL[15 + e] + f4 * wqL[20 + e]) * qsc;
    #pragma unroll
    for (int c = 0; c < 3; ++c)
      ciL[tid * 3 + c] = ldf(coors, row * 3 + c, f32);
  }

  // ---- two-hop masks for the 16 owned rows (each row built exactly once)
  int g = tid >> 6, lane = tid & 63;
  int w = lane & 15, grp = lane >> 4;
  const u64* basep = adjbits + (size_t)b * NN * 16;
  for (int rr = 0; rr < 4; ++rr) {
    int il = g * 4 + rr;            // local row 0..15
    int i = chunk * 16 + il;        // batch row 0..1023
    u64 rw = basep[(size_t)i * 16 + w];
    unsigned short* list = listL[g];
    int cnt = 0;
    #pragma unroll
    for (int sw = 0; sw < 16; ++sw) {
      u64 bits = __shfl(rw, sw, 64);
      int mybit = (int)((bits >> lane) & 1ull);
      int pre = __popcll(bits & ((1ull << lane) - 1ull));
      if (mybit) list[cnt + pre] = (unsigned short)(sw * 64 + lane);
      cnt += __popcll(bits);
    }
    __syncthreads();
    u64 acc = rw;
    if (w == (i >> 6)) acc |= 1ull << (i & 63);
    for (int n = grp; n < cnt; n += 4) acc |= basep[(size_t)list[n] * 16 + w];
    acc |= __shfl_xor(acc, 16, 64);
    acc |= __shfl_xor(acc, 32, 64);
    if (lane < 16) neighL[il][lane] = acc;
    __syncthreads();
  }

  // ---- attention over the full j range
  float q[4][DD], ci[4][3], l[4], A[4][DD];
  #pragma unroll
  for (int r = 0; r < 4; ++r) {
    #pragma unroll
    for (int e = 0; e < DD; ++e) q[r][e] = qL[(g * 4 + r) * DD + e];
    #pragma unroll
    for (int c = 0; c < 3; ++c) ci[r][c] = ciL[(g * 4 + r) * 3 + c];
    l[r] = 0.0f;
    #pragma unroll
    for (int e = 0; e < DD; ++e) A[r][e] = 0.0f;
  }
  float Cf = sConst[0], br2f = sConst[1];
  for (int it = 0; it < 16; ++it) {
    int j = it * 64 + lane;
    float4 ka = kvL[j * 3 + 0];
    float4 kb = kvL[j * 3 + 1];
    float4 kc = kvL[j * 3 + 2];
    float jx = kc.z, jy = kc.w, jz = czL[j];
    u64 nw[4];
    #pragma unroll
    for (int r = 0; r < 4; ++r) nw[r] = neighL[g * 4 + r][it];
    if (fast) {
      #pragma unroll
      for (int r = 0; r < 4; ++r) {
        float cx = jx - ci[r][0], cy = jy - ci[r][1], cz = jz - ci[r][2];
        float dist =
            __builtin_amdgcn_sqrtf(fmaf(cx, cx, fmaf(cy, cy, fmaf(cz, cz, 1e-8f))));
        float s = fmaf(q[r][0], ka.x, br2f);
        s = fmaf(q[r][1], ka.y, s);
        s = fmaf(q[r][2], ka.z, s);
        s = fmaf(q[r][3], ka.w, s);
        s = fmaf(q[r][4], kb.x, s);
        s = fmaf(Cf, dist, s);
        s = fminf(s, 126.0f);
        s = ((nw[r] >> lane) & 1ull) ? s : -150.0f;
        float p = __builtin_amdgcn_exp2f(s);
        l[r] += p;
        A[r][0] = fmaf(p, kb.y, A[r][0]);
        A[r][1] = fmaf(p, kb.z, A[r][1]);
        A[r][2] = fmaf(p, kb.w, A[r][2]);
        A[r][3] = fmaf(p, kc.x, A[r][3]);
        A[r][4] = fmaf(p, kc.y, A[r][4]);
      }
    } else {
      #pragma unroll
      for (int r = 0; r < 4; ++r) {
        float cx = jx - ci[r][0], cy = jy - ci[r][1], cz = jz - ci[r][2];
        float dist = sqrtf(fmaf(cx, cx, fmaf(cy, cy, fmaf(cz, cz, 1e-8f))));
        float rb = ldf(br2, 0, f32);
        #pragma unroll
        for (int h = 0; h < RH; ++h)
          rb += fmaxf(dist * wrL[0][h] + wrL[1][h], 0.0f) * wrL[2][h];
        float s = fmaf(q[r][0], ka.x, rb);
        s = fmaf(q[r][1], ka.y, s);
        s = fmaf(q[r][2], ka.z, s);
        s = fmaf(q[r][3], ka.w, s);
        s = fmaf(q[r][4], kb.x, s);
        s = fminf(s, 85.0f);
        s = ((nw[r] >> lane) & 1ull) ? s : -100.0f;
        float p = __expf(s);
        l[r] += p;
        A[r][0] = fmaf(p, kb.y, A[r][0]);
        A[r][1] = fmaf(p, kb.z, A[r][1]);
        A[r][2] = fmaf(p, kb.w, A[r][2]);
        A[r][3] = fmaf(p, kc.x, A[r][3]);
        A[r][4] = fmaf(p, kc.y, A[r][4]);
      }
    }
  }
  #pragma unroll
  for (int msk = 1; msk < 64; msk <<= 1) {
    #pragma unroll
    for (int r = 0; r < 4; ++r) {
      l[r] += __shfl_xor(l[r], msk, 64);
      A[r][0] += __shfl_xor(A[r][0], msk, 64);
      A[r][1] += __shfl_xor(A[r][1], msk, 64);
      A[r][2] += __shfl_xor(A[r][2], msk, 64);
      A[r][3] += __shfl_xor(A[r][3], msk, 64);
      A[r][4] += __shfl_xor(A[r][4], msk, 64);
    }
  }

  // ---- per-row contribution (denominator is complete) -> block-partial pool
  float* waveC = (float*)listL;             // [4][5], listL dead after twohop
  if (lane == 0) {
    float cw[DD] = {0.f, 0.f, 0.f, 0.f, 0.f};
    #pragma unroll
    for (int r = 0; r < 4; ++r) {
      long long grow = (long long)b * NN + chunk * 16 + g * 4 + r;
      float inv = (l[r] > 0.0f) ? 1.0f / l[r] : 0.0f;
      #pragma unroll
      for (int e = 0; e < DD; ++e)
        cw[e] += ldf(feats, grow * DD + e, f32) + A[r][e] * inv;
    }
    #pragma unroll
    for (int e = 0; e < DD; ++e) waveC[g * DD + e] = cw[e];
  }
  __syncthreads();
  if (tid < DD) {
    float s = waveC[tid] + waveC[DD + tid] + waveC[2 * DD + tid] +
              waveC[3 * DD + tid];
    float old = atomicAdd(&pooled[b * DD + tid], s);  // device-scope, coherent
    asm volatile("" :: "v"(old));  // consume return -> add completed before cnt
  }
  __syncthreads();  // vmcnt drain: all 5 pooled adds done before counter bump
  if (tid == 0) sLast = (atomicAdd(&cntr[b], 1) == 63) ? 1 : 0;
  __syncthreads();

  // ---- last block for this b runs the pooled MLP (replaces k_final)
  if (sLast) {
    float* hL = ((float*)listL) + 32;  // 128 floats, after waveC
    if (tid < DD) {
      // agent-scope load: bypass potentially-stale local L2 (poison fill)
      float pv = __hip_atomic_load(&pooled[b * DD + tid], __ATOMIC_RELAXED,
                                   __HIP_MEMORY_SCOPE_AGENT);
      qL[tid] = pv * (1.0f / 1024.0f);
    }
    __syncthreads();
    if (tid < 128) {
      float acc = ldf(b1, tid, f32);
      #pragma unroll
      for (int d = 0; d < DD; ++d)
        acc = fmaf(qL[d], ldf(w1, d * 128 + tid, f32), acc);
      hL[tid] = fmaxf(acc, 0.0f);
    }
    __syncthreads();
    if (tid < 3) {
      float s = ldf(b2, tid, f32);
      for (int j = 0; j < 128; ++j)
        s = fmaf(hL[j], ldf(w2, j * 3 + tid, f32), s);
      out[b * 3 + tid] = s;
    }
  }
}

// ---------------------------------------------------------------- launch
extern "C" void kernel_launch(void* const* d_in, const int* in_sizes, int n_in,
                              void* d_out, int out_size, void* d_ws, size_t ws_size,
                              hipStream_t stream) {
  const void* adj = d_in[2];
  float* out = (float*)d_out;

  char* w = (char*)d_ws;
  int* gflags = (int*)w;                               // 16 B
  float* pooled = (float*)(w + 64);                    // 320 B
  int* cntr = (int*)(w + 512);                         // 64 B
  const size_t MB2 = (size_t)BB * NN * 16 * sizeof(u64);  // 2 MiB
  u64* adjbits = (u64*)(w + 1024);
  float4* kvg = (float4*)(w + 1024 + MB2);             // 768 KiB
  float* czg = (float*)(w + 1024 + MB2 + 786432);      // 64 KiB

  k_pack<<<PACK_BLOCKS + KV_BLOCKS, 256, 0, stream>>>(
      adj, d_in[0], d_in[1], d_in[4], d_in[5], d_in[6], adjbits, kvg, czg,
      gflags, pooled, cntr);
  k_attn<<<BB * 64, 256, 0, stream>>>(
      d_in[0], d_in[1], d_in[3], d_in[7], d_in[8], d_in[9], d_in[10], kvg, czg,
      gflags, adjbits, pooled, cntr, d_in[11], d_in[12], d_in[13], d_in[14],
      out);
}

// Round 2
// 191.819 us; speedup vs baseline: 1.0540x; 1.0540x over previous
//
#include <hip/hip_runtime.h>
#include <hip/hip_bf16.h>

#define BB 16
#define NN 1024
#define DD 5
#define RH 8

typedef unsigned long long u64;
typedef unsigned int u32;
typedef __hip_bfloat16 bf16;

static __device__ __forceinline__ float tof(bf16 x) { return __bfloat162float(x); }
// runtime-dtype load: f32 storage if f==true else bf16
static __device__ __forceinline__ float ldf(const void* p, long long i, bool f) {
  return f ? ((const float*)p)[i] : tof(((const bf16*)p)[i]);
}

#define LOG2E 1.4426950408889634f
#define PACK_BLOCKS (BB * NN * 16 / 256)  // 1024
#define KV_BLOCKS (BB * NN / 256)         // 64

// Round 14: fix the fused k_attn's latency-boundness (r13: 82us, occ 17%,
// VALUBusy 25% -> stall-dominated at 2 blocks/CU from 63KB LDS).
//  - NO kv LDS staging: kvg (832KB) is L2-resident and the 4 waves of a
//    block read the same j-stream (L1 dedup). Guide lesson #7.
//  - barrier-free two-hop: listL/neighL are per-wave partitioned; wave64
//    lockstep + in-order DS pipe make the RAW safe without __syncthreads.
//  - LDS 63KB -> ~12KB; occupancy becomes VGPR-bound (~16-20 waves/CU).
//  Kept verified round-13 machinery: atomic pool + cntr + last-block MLP,
//  k_pack dtype probe, exp2/log2e folding, collapsed radial MLP.

// ---------------------------------------------------------------- pack + kv
__global__ __launch_bounds__(256) void k_pack(
    const void* __restrict__ adj, const void* __restrict__ feats,
    const void* __restrict__ coors,
    const void* __restrict__ Wk, const void* __restrict__ Wv,
    const void* __restrict__ Wo,
    u64* __restrict__ adjbits, float4* __restrict__ kvg,
    float* __restrict__ czg, int* __restrict__ gflags,
    float* __restrict__ pooled, int* __restrict__ cntr) {
  __shared__ int sNon01, sNonpair, sLow3;
  __shared__ int sCnt[4];
  __shared__ float wkL[25], wvL[25], woL[25];
  int tid = threadIdx.x;

  if (blockIdx.x >= PACK_BLOCKS) {
    // ---------------- kv precompute role ----------------
    int kb = blockIdx.x - PACK_BLOCKS;
    if (kb == 0) {
      // zero pooled accumulators + block counters (workspace is poisoned
      // between iterations); kernel-end flush publishes to k_attn.
      if (tid < BB * DD) pooled[tid] = 0.0f;
      else if (tid < BB * DD + BB) cntr[tid - BB * DD] = 0;
    }
    {
      u32 x = ((const u32*)feats)[tid];
      u32 lo = x & 0xFFFFu;
      int e = (int)((lo >> 7) & 0xFFu);
      bool insane = !(lo == 0u || (e >= 90 && e <= 150));
      u64 m = __ballot(insane);
      if ((tid & 63) == 0) sCnt[tid >> 6] = (int)__popcll(m);
    }
    __syncthreads();
    bool f32 = (sCnt[0] + sCnt[1] + sCnt[2] + sCnt[3]) > 64;
    if (tid < 25) {
      wkL[tid] = ldf(Wk, tid, f32);
      wvL[tid] = ldf(Wv, tid, f32);
      woL[tid] = ldf(Wo, tid, f32);
    }
    if (kb == 0 && tid == 0) gflags[0] = f32 ? 1 : 0;
    __syncthreads();
    long long node = (long long)kb * 256 + tid;  // < BB*NN
    float f0 = ldf(feats, node * DD + 0, f32), f1 = ldf(feats, node * DD + 1, f32),
          f2 = ldf(feats, node * DD + 2, f32), f3 = ldf(feats, node * DD + 3, f32),
          f4 = ldf(feats, node * DD + 4, f32);
    float k[DD], tv[DD], v[DD];
    #pragma unroll
    for (int e = 0; e < DD; ++e) {
      k[e] = f0 * wkL[e] + f1 * wkL[5 + e] + f2 * wkL[10 + e] + f3 * wkL[15 + e] +
             f4 * wkL[20 + e];
      tv[e] = f0 * wvL[e] + f1 * wvL[5 + e] + f2 * wvL[10 + e] + f3 * wvL[15 + e] +
              f4 * wvL[20 + e];
    }
    #pragma unroll
    for (int e = 0; e < DD; ++e)
      v[e] = tv[0] * woL[e] + tv[1] * woL[5 + e] + tv[2] * woL[10 + e] +
             tv[3] * woL[15 + e] + tv[4] * woL[20 + e];
    float cx = ldf(coors, node * 3 + 0, f32);
    float cy = ldf(coors, node * 3 + 1, f32);
    float cz = ldf(coors, node * 3 + 2, f32);
    kvg[node * 3 + 0] = make_float4(k[0], k[1], k[2], k[3]);
    kvg[node * 3 + 1] = make_float4(k[4], v[0], v[1], v[2]);
    kvg[node * 3 + 2] = make_float4(v[3], v[4], cx, cy);
    czg[node] = cz;
    return;
  }

  // ---------------- adjacency pack role ----------------
  if (tid == 0) { sNon01 = 0; sNonpair = 0; sLow3 = 0; }
  __syncthreads();
  {
    const u32* aw = (const u32*)adj;
    int non01 = 0, nonpair = 0, low3 = 0;
    for (int i = tid; i < 4096; i += 256) {
      u32 x = aw[i];
      u32 lo = x & 0xFFFFu, hi = x >> 16;
      non01 |= (x > 1u);
      nonpair |= !((lo == 0u || lo == 0x3F80u) && (hi == 0u || hi == 0x3F80u));
      low3 |= (lo == 0x3F80u);
    }
    if (non01) atomicOr(&sNon01, 1);
    if (nonpair) atomicOr(&sNonpair, 1);
    if (low3) atomicOr(&sLow3, 1);
  }
  __syncthreads();
  // mode: 0=int32, 1=byte, 2=bf16, 3=f32
  int mode;
  if (!sNon01) mode = 0;
  else if (!sNonpair) mode = sLow3 ? 2 : 3;
  else mode = 1;

  int gid = blockIdx.x * 256 + tid;
  int w = gid & 15;
  long long row = gid >> 4;
  long long base = row * NN + (long long)w * 64;
  u64 bits = 0;
  if (mode == 3) {
    const uint4* p = (const uint4*)((const float*)adj + base);
    #pragma unroll
    for (int t = 0; t < 16; ++t) {
      uint4 x = p[t];
      if (x.x << 1) bits |= 1ull << (4 * t + 0);   // ignore -0.0
      if (x.y << 1) bits |= 1ull << (4 * t + 1);
      if (x.z << 1) bits |= 1ull << (4 * t + 2);
      if (x.w << 1) bits |= 1ull << (4 * t + 3);
    }
  } else if (mode == 0) {
    const uint4* p = (const uint4*)((const u32*)adj + base);
    #pragma unroll
    for (int t = 0; t < 16; ++t) {
      uint4 x = p[t];
      if (x.x) bits |= 1ull << (4 * t + 0);
      if (x.y) bits |= 1ull << (4 * t + 1);
      if (x.z) bits |= 1ull << (4 * t + 2);
      if (x.w) bits |= 1ull << (4 * t + 3);
    }
  } else if (mode == 2) {
    const uint4* p = (const uint4*)((const unsigned short*)adj + base);
    #pragma unroll
    for (int t = 0; t < 8; ++t) {
      uint4 x = p[t];
      u32 c[4] = {x.x, x.y, x.z, x.w};
      #pragma unroll
      for (int q = 0; q < 4; ++q) {
        if ((c[q] & 0x7FFFu)) bits |= 1ull << (8 * t + 2 * q + 0);
        if ((c[q] >> 16) & 0x7FFFu) bits |= 1ull << (8 * t + 2 * q + 1);
      }
    }
  } else {
    const uint4* p = (const uint4*)((const unsigned char*)adj + base);
    #pragma unroll
    for (int t = 0; t < 4; ++t) {
      uint4 x = p[t];
      u32 c[4] = {x.x, x.y, x.z, x.w};
      #pragma unroll
      for (int q = 0; q < 4; ++q)
        #pragma unroll
        for (int bb = 0; bb < 4; ++bb)
          if ((c[q] >> (8 * bb)) & 0xFFu) bits |= 1ull << (16 * t + 4 * q + bb);
    }
  }
  adjbits[gid] = bits;
}

// ---------------- fused: two-hop + attention + pool + last-block MLP
__global__ __launch_bounds__(256) void k_attn(
    const void* __restrict__ feats, const void* __restrict__ coors,
    const void* __restrict__ Wq,
    const void* __restrict__ wr1, const void* __restrict__ br1,
    const void* __restrict__ wr2, const void* __restrict__ br2,
    const float4* __restrict__ kvg, const float* __restrict__ czg,
    const int* __restrict__ gflags, const u64* __restrict__ adjbits,
    float* __restrict__ pooled, int* __restrict__ cntr,
    const void* __restrict__ w1, const void* __restrict__ b1,
    const void* __restrict__ w2, const void* __restrict__ b2,
    float* __restrict__ out) {
  __shared__ unsigned short listL[4][NN];  // 8 KB, per-wave partitioned
  __shared__ u64 neighL[16][16];           // 2 KB, rows partitioned per-wave
  __shared__ float qL[16 * DD], ciL[16 * 3];
  __shared__ float wqL[25];
  __shared__ float wrL[3][RH];
  __shared__ float sConst[2];
  __shared__ int sFast, sLast;
  __shared__ float waveC[4][DD];
  __shared__ float pM[DD];
  __shared__ float hL[128];

  int bi = blockIdx.x;
  int b = bi >> 6, chunk = bi & 63;  // 64 chunks of 16 rows, full j range
  int tid = threadIdx.x;
  bool f32 = gflags[0] != 0;
  if (tid < 25) wqL[tid] = ldf(Wq, tid, f32);
  if (tid >= 64 && tid < 64 + RH) {
    int h = tid - 64;
    wrL[0][h] = ldf(wr1, h, f32);
    wrL[1][h] = ldf(br1, h, f32);
    wrL[2][h] = ldf(wr2, h, f32);
  }
  if (tid == 96) {
    float c = 0.0f;
    int ok = 1;
    #pragma unroll
    for (int h = 0; h < RH; ++h) {
      float w1h = ldf(wr1, h, f32);
      if (ldf(br1, h, f32) != 0.0f) ok = 0;
      if (w1h > 0.0f) c += w1h * ldf(wr2, h, f32);
    }
    sConst[0] = c * LOG2E;
    sConst[1] = ldf(br2, 0, f32) * LOG2E;
    sFast = ok;
  }
  __syncthreads();
  int fast = sFast;
  // q (scaled) + ci for this chunk's 16 rows
  if (tid < 16) {
    long long row = (long long)b * NN + chunk * 16 + tid;
    float f0 = ldf(feats, row * DD + 0, f32), f1 = ldf(feats, row * DD + 1, f32),
          f2 = ldf(feats, row * DD + 2, f32), f3 = ldf(feats, row * DD + 3, f32),
          f4 = ldf(feats, row * DD + 4, f32);
    float qsc = fast ? (0.4472135954999579f * LOG2E) : 0.4472135954999579f;
    #pragma unroll
    for (int e = 0; e < DD; ++e)
      qL[tid * DD + e] = (f0 * wqL[e] + f1 * wqL[5 + e] + f2 * wqL[10 + e] +
                          f3 * wqL[15 + e] + f4 * wqL[20 + e]) * qsc;
    #pragma unroll
    for (int c = 0; c < 3; ++c)
      ciL[tid * 3 + c] = ldf(coors, row * 3 + c, f32);
  }
  __syncthreads();

  // ---- two-hop masks, barrier-free (per-wave lists and rows)
  int g = tid >> 6, lane = tid & 63;
  int w = lane & 15, grp = lane >> 4;
  const u64* basep = adjbits + (size_t)b * NN * 16;
  for (int rr = 0; rr < 4; ++rr) {
    int il = g * 4 + rr;            // local row 0..15, owned by wave g
    int i = chunk * 16 + il;        // batch row
    u64 rw = basep[(size_t)i * 16 + w];
    unsigned short* list = listL[g];
    int cnt = 0;
    #pragma unroll
    for (int sw = 0; sw < 16; ++sw) {
      u64 bits = __shfl(rw, sw, 64);
      int mybit = (int)((bits >> lane) & 1ull);
      int pre = __popcll(bits & ((1ull << lane) - 1ull));
      if (mybit) list[cnt + pre] = (unsigned short)(sw * 64 + lane);
      cnt += __popcll(bits);
    }
    u64 acc = rw;
    if (w == (i >> 6)) acc |= 1ull << (i & 63);
    for (int n = grp; n < cnt; n += 4) acc |= basep[(size_t)list[n] * 16 + w];
    acc |= __shfl_xor(acc, 16, 64);
    acc |= __shfl_xor(acc, 32, 64);
    if (lane < 16) neighL[il][lane] = acc;
  }

  // ---- attention over full j range, kv direct from L2 (no LDS staging)
  float q[4][DD], ci[4][3], l[4], A[4][DD];
  #pragma unroll
  for (int r = 0; r < 4; ++r) {
    #pragma unroll
    for (int e = 0; e < DD; ++e) q[r][e] = qL[(g * 4 + r) * DD + e];
    #pragma unroll
    for (int c = 0; c < 3; ++c) ci[r][c] = ciL[(g * 4 + r) * 3 + c];
    l[r] = 0.0f;
    #pragma unroll
    for (int e = 0; e < DD; ++e) A[r][e] = 0.0f;
  }
  const float4* kvb = kvg + (size_t)b * NN * 3;
  const float* czb = czg + (size_t)b * NN;
  float Cf = sConst[0], br2f = sConst[1];
  for (int it = 0; it < 16; ++it) {
    int j = it * 64 + lane;
    float4 ka = kvb[j * 3 + 0];
    float4 kb = kvb[j * 3 + 1];
    float4 kc = kvb[j * 3 + 2];
    float jx = kc.z, jy = kc.w, jz = czb[j];
    u64 nw[4];
    #pragma unroll
    for (int r = 0; r < 4; ++r) nw[r] = neighL[g * 4 + r][it];
    if (fast) {
      #pragma unroll
      for (int r = 0; r < 4; ++r) {
        float cx = jx - ci[r][0], cy = jy - ci[r][1], cz = jz - ci[r][2];
        float dist =
            __builtin_amdgcn_sqrtf(fmaf(cx, cx, fmaf(cy, cy, fmaf(cz, cz, 1e-8f))));
        float s = fmaf(q[r][0], ka.x, br2f);
        s = fmaf(q[r][1], ka.y, s);
        s = fmaf(q[r][2], ka.z, s);
        s = fmaf(q[r][3], ka.w, s);
        s = fmaf(q[r][4], kb.x, s);
        s = fmaf(Cf, dist, s);
        s = fminf(s, 126.0f);
        s = ((nw[r] >> lane) & 1ull) ? s : -150.0f;
        float p = __builtin_amdgcn_exp2f(s);
        l[r] += p;
        A[r][0] = fmaf(p, kb.y, A[r][0]);
        A[r][1] = fmaf(p, kb.z, A[r][1]);
        A[r][2] = fmaf(p, kb.w, A[r][2]);
        A[r][3] = fmaf(p, kc.x, A[r][3]);
        A[r][4] = fmaf(p, kc.y, A[r][4]);
      }
    } else {
      #pragma unroll
      for (int r = 0; r < 4; ++r) {
        float cx = jx - ci[r][0], cy = jy - ci[r][1], cz = jz - ci[r][2];
        float dist = sqrtf(fmaf(cx, cx, fmaf(cy, cy, fmaf(cz, cz, 1e-8f))));
        float rb = ldf(br2, 0, f32);
        #pragma unroll
        for (int h = 0; h < RH; ++h)
          rb += fmaxf(dist * wrL[0][h] + wrL[1][h], 0.0f) * wrL[2][h];
        float s = fmaf(q[r][0], ka.x, rb);
        s = fmaf(q[r][1], ka.y, s);
        s = fmaf(q[r][2], ka.z, s);
        s = fmaf(q[r][3], ka.w, s);
        s = fmaf(q[r][4], kb.x, s);
        s = fminf(s, 85.0f);
        s = ((nw[r] >> lane) & 1ull) ? s : -100.0f;
        float p = __expf(s);
        l[r] += p;
        A[r][0] = fmaf(p, kb.y, A[r][0]);
        A[r][1] = fmaf(p, kb.z, A[r][1]);
        A[r][2] = fmaf(p, kb.w, A[r][2]);
        A[r][3] = fmaf(p, kc.x, A[r][3]);
        A[r][4] = fmaf(p, kc.y, A[r][4]);
      }
    }
  }
  #pragma unroll
  for (int msk = 1; msk < 64; msk <<= 1) {
    #pragma unroll
    for (int r = 0; r < 4; ++r) {
      l[r] += __shfl_xor(l[r], msk, 64);
      A[r][0] += __shfl_xor(A[r][0], msk, 64);
      A[r][1] += __shfl_xor(A[r][1], msk, 64);
      A[r][2] += __shfl_xor(A[r][2], msk, 64);
      A[r][3] += __shfl_xor(A[r][3], msk, 64);
      A[r][4] += __shfl_xor(A[r][4], msk, 64);
    }
  }

  // ---- per-row contribution (denominator complete) -> block-partial pool
  if (lane == 0) {
    float cw[DD] = {0.f, 0.f, 0.f, 0.f, 0.f};
    #pragma unroll
    for (int r = 0; r < 4; ++r) {
      long long grow = (long long)b * NN + chunk * 16 + g * 4 + r;
      float inv = (l[r] > 0.0f) ? 1.0f / l[r] : 0.0f;
      #pragma unroll
      for (int e = 0; e < DD; ++e)
        cw[e] += ldf(feats, grow * DD + e, f32) + A[r][e] * inv;
    }
    #pragma unroll
    for (int e = 0; e < DD; ++e) waveC[g][e] = cw[e];
  }
  __syncthreads();
  if (tid < DD) {
    float s = waveC[0][tid] + waveC[1][tid] + waveC[2][tid] + waveC[3][tid];
    float old = atomicAdd(&pooled[b * DD + tid], s);  // device-scope, coherent
    asm volatile("" :: "v"(old));  // consume return -> add completed before cnt
  }
  __syncthreads();  // vmcnt drain: all 5 pooled adds done before counter bump
  if (tid == 0) sLast = (atomicAdd(&cntr[b], 1) == 63) ? 1 : 0;
  __syncthreads();

  // ---- last block for this b runs the pooled MLP
  if (sLast) {
    if (tid < DD) {
      // agent-scope load: bypass potentially-stale local L2
      float pv = __hip_atomic_load(&pooled[b * DD + tid], __ATOMIC_RELAXED,
                                   __HIP_MEMORY_SCOPE_AGENT);
      pM[tid] = pv * (1.0f / 1024.0f);
    }
    __syncthreads();
    if (tid < 128) {
      float acc = ldf(b1, tid, f32);
      #pragma unroll
      for (int d = 0; d < DD; ++d)
        acc = fmaf(pM[d], ldf(w1, d * 128 + tid, f32), acc);
      hL[tid] = fmaxf(acc, 0.0f);
    }
    __syncthreads();
    if (tid < 3) {
      float s = ldf(b2, tid, f32);
      for (int j = 0; j < 128; ++j)
        s = fmaf(hL[j], ldf(w2, j * 3 + tid, f32), s);
      out[b * 3 + tid] = s;
    }
  }
}

// ---------------------------------------------------------------- launch
extern "C" void kernel_launch(void* const* d_in, const int* in_sizes, int n_in,
                              void* d_out, int out_size, void* d_ws, size_t ws_size,
                              hipStream_t stream) {
  const void* adj = d_in[2];
  float* out = (float*)d_out;

  char* w = (char*)d_ws;
  int* gflags = (int*)w;                               // 16 B
  float* pooled = (float*)(w + 64);                    // 320 B
  int* cntr = (int*)(w + 512);                         // 64 B
  const size_t MB2 = (size_t)BB * NN * 16 * sizeof(u64);  // 2 MiB
  u64* adjbits = (u64*)(w + 1024);
  float4* kvg = (float4*)(w + 1024 + MB2);             // 768 KiB
  float* czg = (float*)(w + 1024 + MB2 + 786432);      // 64 KiB

  k_pack<<<PACK_BLOCKS + KV_BLOCKS, 256, 0, stream>>>(
      adj, d_in[0], d_in[1], d_in[4], d_in[5], d_in[6], adjbits, kvg, czg,
      gflags, pooled, cntr);
  k_attn<<<BB * 64, 256, 0, stream>>>(
      d_in[0], d_in[1], d_in[3], d_in[7], d_in[8], d_in[9], d_in[10], kvg, czg,
      gflags, adjbits, pooled, cntr, d_in[11], d_in[12], d_in[13], d_in[14],
      out);
}

// Round 3
// 190.664 us; speedup vs baseline: 1.0604x; 1.0061x over previous
//
#include <hip/hip_runtime.h>
#include <hip/hip_bf16.h>

#define BB 16
#define NN 1024
#define DD 5
#define RH 8

typedef unsigned long long u64;
typedef unsigned int u32;
typedef __hip_bfloat16 bf16;

static __device__ __forceinline__ float tof(bf16 x) { return __bfloat162float(x); }
// runtime-dtype load: f32 storage if f==true else bf16
static __device__ __forceinline__ float ldf(const void* p, long long i, bool f) {
  return f ? ((const float*)p)[i] : tof(((const bf16*)p)[i]);
}

#define LOG2E 1.4426950408889634f
#define PACK_BLOCKS (BB * NN * 16 / 256)  // 1024
#define KV_BLOCKS (BB * NN / 256)         // 64

// Round 15: k_attn is grid-capped, not LDS-capped (r14: 68.9us, occ 20%,
// VALUBusy 29%; 1024 blocks x 4 waves = 16 waves/CU = 50% hard ceiling, and
// the j-loop's dependent L2 loads aren't hidden at that residency).
//  - grid BB*128 = 2048 blocks, 8 rows/block, 2 rows/wave: total pair-work
//    unchanged, wave count doubles (32/CU offered), VGPRs drop ~28.
//  - manual 1-deep kv prefetch in the j-loop (load it+1 while computing it).
//  Kept: barrier-free two-hop, no kv LDS staging, atomic pool + last-block
//  MLP (cntr target now 127), k_pack dtype probe, exp2/log2e folding.

// ---------------------------------------------------------------- pack + kv
__global__ __launch_bounds__(256) void k_pack(
    const void* __restrict__ adj, const void* __restrict__ feats,
    const void* __restrict__ coors,
    const void* __restrict__ Wk, const void* __restrict__ Wv,
    const void* __restrict__ Wo,
    u64* __restrict__ adjbits, float4* __restrict__ kvg,
    float* __restrict__ czg, int* __restrict__ gflags,
    float* __restrict__ pooled, int* __restrict__ cntr) {
  __shared__ int sNon01, sNonpair, sLow3;
  __shared__ int sCnt[4];
  __shared__ float wkL[25], wvL[25], woL[25];
  int tid = threadIdx.x;

  if (blockIdx.x >= PACK_BLOCKS) {
    // ---------------- kv precompute role ----------------
    int kb = blockIdx.x - PACK_BLOCKS;
    if (kb == 0) {
      // zero pooled accumulators + block counters (workspace is poisoned
      // between iterations); kernel-end flush publishes to k_attn.
      if (tid < BB * DD) pooled[tid] = 0.0f;
      else if (tid < BB * DD + BB) cntr[tid - BB * DD] = 0;
    }
    {
      u32 x = ((const u32*)feats)[tid];
      u32 lo = x & 0xFFFFu;
      int e = (int)((lo >> 7) & 0xFFu);
      bool insane = !(lo == 0u || (e >= 90 && e <= 150));
      u64 m = __ballot(insane);
      if ((tid & 63) == 0) sCnt[tid >> 6] = (int)__popcll(m);
    }
    __syncthreads();
    bool f32 = (sCnt[0] + sCnt[1] + sCnt[2] + sCnt[3]) > 64;
    if (tid < 25) {
      wkL[tid] = ldf(Wk, tid, f32);
      wvL[tid] = ldf(Wv, tid, f32);
      woL[tid] = ldf(Wo, tid, f32);
    }
    if (kb == 0 && tid == 0) gflags[0] = f32 ? 1 : 0;
    __syncthreads();
    long long node = (long long)kb * 256 + tid;  // < BB*NN
    float f0 = ldf(feats, node * DD + 0, f32), f1 = ldf(feats, node * DD + 1, f32),
          f2 = ldf(feats, node * DD + 2, f32), f3 = ldf(feats, node * DD + 3, f32),
          f4 = ldf(feats, node * DD + 4, f32);
    float k[DD], tv[DD], v[DD];
    #pragma unroll
    for (int e = 0; e < DD; ++e) {
      k[e] = f0 * wkL[e] + f1 * wkL[5 + e] + f2 * wkL[10 + e] + f3 * wkL[15 + e] +
             f4 * wkL[20 + e];
      tv[e] = f0 * wvL[e] + f1 * wvL[5 + e] + f2 * wvL[10 + e] + f3 * wvL[15 + e] +
              f4 * wvL[20 + e];
    }
    #pragma unroll
    for (int e = 0; e < DD; ++e)
      v[e] = tv[0] * woL[e] + tv[1] * woL[5 + e] + tv[2] * woL[10 + e] +
             tv[3] * woL[15 + e] + tv[4] * woL[20 + e];
    float cx = ldf(coors, node * 3 + 0, f32);
    float cy = ldf(coors, node * 3 + 1, f32);
    float cz = ldf(coors, node * 3 + 2, f32);
    kvg[node * 3 + 0] = make_float4(k[0], k[1], k[2], k[3]);
    kvg[node * 3 + 1] = make_float4(k[4], v[0], v[1], v[2]);
    kvg[node * 3 + 2] = make_float4(v[3], v[4], cx, cy);
    czg[node] = cz;
    return;
  }

  // ---------------- adjacency pack role ----------------
  if (tid == 0) { sNon01 = 0; sNonpair = 0; sLow3 = 0; }
  __syncthreads();
  {
    const u32* aw = (const u32*)adj;
    int non01 = 0, nonpair = 0, low3 = 0;
    for (int i = tid; i < 4096; i += 256) {
      u32 x = aw[i];
      u32 lo = x & 0xFFFFu, hi = x >> 16;
      non01 |= (x > 1u);
      nonpair |= !((lo == 0u || lo == 0x3F80u) && (hi == 0u || hi == 0x3F80u));
      low3 |= (lo == 0x3F80u);
    }
    if (non01) atomicOr(&sNon01, 1);
    if (nonpair) atomicOr(&sNonpair, 1);
    if (low3) atomicOr(&sLow3, 1);
  }
  __syncthreads();
  // mode: 0=int32, 1=byte, 2=bf16, 3=f32
  int mode;
  if (!sNon01) mode = 0;
  else if (!sNonpair) mode = sLow3 ? 2 : 3;
  else mode = 1;

  int gid = blockIdx.x * 256 + tid;
  int w = gid & 15;
  long long row = gid >> 4;
  long long base = row * NN + (long long)w * 64;
  u64 bits = 0;
  if (mode == 3) {
    const uint4* p = (const uint4*)((const float*)adj + base);
    #pragma unroll
    for (int t = 0; t < 16; ++t) {
      uint4 x = p[t];
      if (x.x << 1) bits |= 1ull << (4 * t + 0);   // ignore -0.0
      if (x.y << 1) bits |= 1ull << (4 * t + 1);
      if (x.z << 1) bits |= 1ull << (4 * t + 2);
      if (x.w << 1) bits |= 1ull << (4 * t + 3);
    }
  } else if (mode == 0) {
    const uint4* p = (const uint4*)((const u32*)adj + base);
    #pragma unroll
    for (int t = 0; t < 16; ++t) {
      uint4 x = p[t];
      if (x.x) bits |= 1ull << (4 * t + 0);
      if (x.y) bits |= 1ull << (4 * t + 1);
      if (x.z) bits |= 1ull << (4 * t + 2);
      if (x.w) bits |= 1ull << (4 * t + 3);
    }
  } else if (mode == 2) {
    const uint4* p = (const uint4*)((const unsigned short*)adj + base);
    #pragma unroll
    for (int t = 0; t < 8; ++t) {
      uint4 x = p[t];
      u32 c[4] = {x.x, x.y, x.z, x.w};
      #pragma unroll
      for (int q = 0; q < 4; ++q) {
        if ((c[q] & 0x7FFFu)) bits |= 1ull << (8 * t + 2 * q + 0);
        if ((c[q] >> 16) & 0x7FFFu) bits |= 1ull << (8 * t + 2 * q + 1);
      }
    }
  } else {
    const uint4* p = (const uint4*)((const unsigned char*)adj + base);
    #pragma unroll
    for (int t = 0; t < 4; ++t) {
      uint4 x = p[t];
      u32 c[4] = {x.x, x.y, x.z, x.w};
      #pragma unroll
      for (int q = 0; q < 4; ++q)
        #pragma unroll
        for (int bb = 0; bb < 4; ++bb)
          if ((c[q] >> (8 * bb)) & 0xFFu) bits |= 1ull << (16 * t + 4 * q + bb);
    }
  }
  adjbits[gid] = bits;
}

// ---------------- fused: two-hop + attention + pool + last-block MLP
__global__ __launch_bounds__(256) void k_attn(
    const void* __restrict__ feats, const void* __restrict__ coors,
    const void* __restrict__ Wq,
    const void* __restrict__ wr1, const void* __restrict__ br1,
    const void* __restrict__ wr2, const void* __restrict__ br2,
    const float4* __restrict__ kvg, const float* __restrict__ czg,
    const int* __restrict__ gflags, const u64* __restrict__ adjbits,
    float* __restrict__ pooled, int* __restrict__ cntr,
    const void* __restrict__ w1, const void* __restrict__ b1,
    const void* __restrict__ w2, const void* __restrict__ b2,
    float* __restrict__ out) {
  __shared__ unsigned short listL[4][NN];  // 8 KB, per-wave partitioned
  __shared__ u64 neighL[8][16];            // 1 KB, rows partitioned per-wave
  __shared__ float qL[8 * DD], ciL[8 * 3];
  __shared__ float wqL[25];
  __shared__ float wrL[3][RH];
  __shared__ float sConst[2];
  __shared__ int sFast, sLast;
  __shared__ float waveC[4][DD];
  __shared__ float pM[DD];
  __shared__ float hL[128];

  int bi = blockIdx.x;
  int b = bi >> 7, chunk = bi & 127;  // 128 chunks of 8 rows, full j range
  int tid = threadIdx.x;
  bool f32 = gflags[0] != 0;
  if (tid < 25) wqL[tid] = ldf(Wq, tid, f32);
  if (tid >= 64 && tid < 64 + RH) {
    int h = tid - 64;
    wrL[0][h] = ldf(wr1, h, f32);
    wrL[1][h] = ldf(br1, h, f32);
    wrL[2][h] = ldf(wr2, h, f32);
  }
  if (tid == 96) {
    float c = 0.0f;
    int ok = 1;
    #pragma unroll
    for (int h = 0; h < RH; ++h) {
      float w1h = ldf(wr1, h, f32);
      if (ldf(br1, h, f32) != 0.0f) ok = 0;
      if (w1h > 0.0f) c += w1h * ldf(wr2, h, f32);
    }
    sConst[0] = c * LOG2E;
    sConst[1] = ldf(br2, 0, f32) * LOG2E;
    sFast = ok;
  }
  __syncthreads();
  int fast = sFast;
  // q (scaled) + ci for this chunk's 8 rows
  if (tid < 8) {
    long long row = (long long)b * NN + chunk * 8 + tid;
    float f0 = ldf(feats, row * DD + 0, f32), f1 = ldf(feats, row * DD + 1, f32),
          f2 = ldf(feats, row * DD + 2, f32), f3 = ldf(feats, row * DD + 3, f32),
          f4 = ldf(feats, row * DD + 4, f32);
    float qsc = fast ? (0.4472135954999579f * LOG2E) : 0.4472135954999579f;
    #pragma unroll
    for (int e = 0; e < DD; ++e)
      qL[tid * DD + e] = (f0 * wqL[e] + f1 * wqL[5 + e] + f2 * wqL[10 + e] +
                          f3 * wqL[15 + e] + f4 * wqL[20 + e]) * qsc;
    #pragma unroll
    for (int c = 0; c < 3; ++c)
      ciL[tid * 3 + c] = ldf(coors, row * 3 + c, f32);
  }
  __syncthreads();

  // ---- two-hop masks, barrier-free (per-wave lists and rows, 2 rows/wave)
  int g = tid >> 6, lane = tid & 63;
  int w = lane & 15, grp = lane >> 4;
  const u64* basep = adjbits + (size_t)b * NN * 16;
  for (int rr = 0; rr < 2; ++rr) {
    int il = g * 2 + rr;            // local row 0..7, owned by wave g
    int i = chunk * 8 + il;         // batch row
    u64 rw = basep[(size_t)i * 16 + w];
    unsigned short* list = listL[g];
    int cnt = 0;
    #pragma unroll
    for (int sw = 0; sw < 16; ++sw) {
      u64 bits = __shfl(rw, sw, 64);
      int mybit = (int)((bits >> lane) & 1ull);
      int pre = __popcll(bits & ((1ull << lane) - 1ull));
      if (mybit) list[cnt + pre] = (unsigned short)(sw * 64 + lane);
      cnt += __popcll(bits);
    }
    u64 acc = rw;
    if (w == (i >> 6)) acc |= 1ull << (i & 63);
    for (int n = grp; n < cnt; n += 4) acc |= basep[(size_t)list[n] * 16 + w];
    acc |= __shfl_xor(acc, 16, 64);
    acc |= __shfl_xor(acc, 32, 64);
    if (lane < 16) neighL[il][lane] = acc;
  }

  // ---- attention over full j range, kv direct from L2, 1-deep prefetch
  float q[2][DD], ci[2][3], l[2], A[2][DD];
  #pragma unroll
  for (int r = 0; r < 2; ++r) {
    #pragma unroll
    for (int e = 0; e < DD; ++e) q[r][e] = qL[(g * 2 + r) * DD + e];
    #pragma unroll
    for (int c = 0; c < 3; ++c) ci[r][c] = ciL[(g * 2 + r) * 3 + c];
    l[r] = 0.0f;
    #pragma unroll
    for (int e = 0; e < DD; ++e) A[r][e] = 0.0f;
  }
  const float4* kvb = kvg + (size_t)b * NN * 3;
  const float* czb = czg + (size_t)b * NN;
  float Cf = sConst[0], br2f = sConst[1];
  int j = lane;
  float4 ka = kvb[j * 3 + 0];
  float4 kb = kvb[j * 3 + 1];
  float4 kc = kvb[j * 3 + 2];
  float jz = czb[j];
  for (int it = 0; it < 16; ++it) {
    float4 nka, nkb, nkc;
    float njz;
    if (it < 15) {  // prefetch next tile while computing this one
      int nj = j + 64;
      nka = kvb[nj * 3 + 0];
      nkb = kvb[nj * 3 + 1];
      nkc = kvb[nj * 3 + 2];
      njz = czb[nj];
    }
    float jx = kc.z, jy = kc.w;
    u64 nw[2];
    #pragma unroll
    for (int r = 0; r < 2; ++r) nw[r] = neighL[g * 2 + r][it];
    if (fast) {
      #pragma unroll
      for (int r = 0; r < 2; ++r) {
        float cx = jx - ci[r][0], cy = jy - ci[r][1], cz = jz - ci[r][2];
        float dist =
            __builtin_amdgcn_sqrtf(fmaf(cx, cx, fmaf(cy, cy, fmaf(cz, cz, 1e-8f))));
        float s = fmaf(q[r][0], ka.x, br2f);
        s = fmaf(q[r][1], ka.y, s);
        s = fmaf(q[r][2], ka.z, s);
        s = fmaf(q[r][3], ka.w, s);
        s = fmaf(q[r][4], kb.x, s);
        s = fmaf(Cf, dist, s);
        s = fminf(s, 126.0f);
        s = ((nw[r] >> lane) & 1ull) ? s : -150.0f;
        float p = __builtin_amdgcn_exp2f(s);
        l[r] += p;
        A[r][0] = fmaf(p, kb.y, A[r][0]);
        A[r][1] = fmaf(p, kb.z, A[r][1]);
        A[r][2] = fmaf(p, kb.w, A[r][2]);
        A[r][3] = fmaf(p, kc.x, A[r][3]);
        A[r][4] = fmaf(p, kc.y, A[r][4]);
      }
    } else {
      #pragma unroll
      for (int r = 0; r < 2; ++r) {
        float cx = jx - ci[r][0], cy = jy - ci[r][1], cz = jz - ci[r][2];
        float dist = sqrtf(fmaf(cx, cx, fmaf(cy, cy, fmaf(cz, cz, 1e-8f))));
        float rb = ldf(br2, 0, f32);
        #pragma unroll
        for (int h = 0; h < RH; ++h)
          rb += fmaxf(dist * wrL[0][h] + wrL[1][h], 0.0f) * wrL[2][h];
        float s = fmaf(q[r][0], ka.x, rb);
        s = fmaf(q[r][1], ka.y, s);
        s = fmaf(q[r][2], ka.z, s);
        s = fmaf(q[r][3], ka.w, s);
        s = fmaf(q[r][4], kb.x, s);
        s = fminf(s, 85.0f);
        s = ((nw[r] >> lane) & 1ull) ? s : -100.0f;
        float p = __expf(s);
        l[r] += p;
        A[r][0] = fmaf(p, kb.y, A[r][0]);
        A[r][1] = fmaf(p, kb.z, A[r][1]);
        A[r][2] = fmaf(p, kb.w, A[r][2]);
        A[r][3] = fmaf(p, kc.x, A[r][3]);
        A[r][4] = fmaf(p, kc.y, A[r][4]);
      }
    }
    if (it < 15) { ka = nka; kb = nkb; kc = nkc; jz = njz; j += 64; }
  }
  #pragma unroll
  for (int msk = 1; msk < 64; msk <<= 1) {
    #pragma unroll
    for (int r = 0; r < 2; ++r) {
      l[r] += __shfl_xor(l[r], msk, 64);
      A[r][0] += __shfl_xor(A[r][0], msk, 64);
      A[r][1] += __shfl_xor(A[r][1], msk, 64);
      A[r][2] += __shfl_xor(A[r][2], msk, 64);
      A[r][3] += __shfl_xor(A[r][3], msk, 64);
      A[r][4] += __shfl_xor(A[r][4], msk, 64);
    }
  }

  // ---- per-row contribution (denominator complete) -> block-partial pool
  if (lane == 0) {
    float cw[DD] = {0.f, 0.f, 0.f, 0.f, 0.f};
    #pragma unroll
    for (int r = 0; r < 2; ++r) {
      long long grow = (long long)b * NN + chunk * 8 + g * 2 + r;
      float inv = (l[r] > 0.0f) ? 1.0f / l[r] : 0.0f;
      #pragma unroll
      for (int e = 0; e < DD; ++e)
        cw[e] += ldf(feats, grow * DD + e, f32) + A[r][e] * inv;
    }
    #pragma unroll
    for (int e = 0; e < DD; ++e) waveC[g][e] = cw[e];
  }
  __syncthreads();
  if (tid < DD) {
    float s = waveC[0][tid] + waveC[1][tid] + waveC[2][tid] + waveC[3][tid];
    float old = atomicAdd(&pooled[b * DD + tid], s);  // device-scope, coherent
    asm volatile("" :: "v"(old));  // consume return -> add completed before cnt
  }
  __syncthreads();  // vmcnt drain: all 5 pooled adds done before counter bump
  if (tid == 0) sLast = (atomicAdd(&cntr[b], 1) == 127) ? 1 : 0;
  __syncthreads();

  // ---- last block for this b runs the pooled MLP
  if (sLast) {
    if (tid < DD) {
      // agent-scope load: bypass potentially-stale local L2
      float pv = __hip_atomic_load(&pooled[b * DD + tid], __ATOMIC_RELAXED,
                                   __HIP_MEMORY_SCOPE_AGENT);
      pM[tid] = pv * (1.0f / 1024.0f);
    }
    __syncthreads();
    if (tid < 128) {
      float acc = ldf(b1, tid, f32);
      #pragma unroll
      for (int d = 0; d < DD; ++d)
        acc = fmaf(pM[d], ldf(w1, d * 128 + tid, f32), acc);
      hL[tid] = fmaxf(acc, 0.0f);
    }
    __syncthreads();
    if (tid < 3) {
      float s = ldf(b2, tid, f32);
      for (int j2 = 0; j2 < 128; ++j2)
        s = fmaf(hL[j2], ldf(w2, j2 * 3 + tid, f32), s);
      out[b * 3 + tid] = s;
    }
  }
}

// ---------------------------------------------------------------- launch
extern "C" void kernel_launch(void* const* d_in, const int* in_sizes, int n_in,
                              void* d_out, int out_size, void* d_ws, size_t ws_size,
                              hipStream_t stream) {
  const void* adj = d_in[2];
  float* out = (float*)d_out;

  char* w = (char*)d_ws;
  int* gflags = (int*)w;                               // 16 B
  float* pooled = (float*)(w + 64);                    // 320 B
  int* cntr = (int*)(w + 512);                         // 64 B
  const size_t MB2 = (size_t)BB * NN * 16 * sizeof(u64);  // 2 MiB
  u64* adjbits = (u64*)(w + 1024);
  float4* kvg = (float4*)(w + 1024 + MB2);             // 768 KiB
  float* czg = (float*)(w + 1024 + MB2 + 786432);      // 64 KiB

  k_pack<<<PACK_BLOCKS + KV_BLOCKS, 256, 0, stream>>>(
      adj, d_in[0], d_in[1], d_in[4], d_in[5], d_in[6], adjbits, kvg, czg,
      gflags, pooled, cntr);
  k_attn<<<BB * 128, 256, 0, stream>>>(
      d_in[0], d_in[1], d_in[3], d_in[7], d_in[8], d_in[9], d_in[10], kvg, czg,
      gflags, adjbits, pooled, cntr, d_in[11], d_in[12], d_in[13], d_in[14],
      out);
}

// Round 4
// 190.237 us; speedup vs baseline: 1.0628x; 1.0022x over previous
//
#include <hip/hip_runtime.h>
#include <hip/hip_bf16.h>

#define BB 16
#define NN 1024
#define DD 5
#define RH 8

typedef unsigned long long u64;
typedef unsigned int u32;
typedef __hip_bfloat16 bf16;

static __device__ __forceinline__ float tof(bf16 x) { return __bfloat162float(x); }
// runtime-dtype load: f32 storage if f==true else bf16
static __device__ __forceinline__ float ldf(const void* p, long long i, bool f) {
  return f ? ((const float*)p)[i] : tof(((const bf16*)p)[i]);
}

#define LOG2E 1.4426950408889634f
#define PACK_BLOCKS (BB * NN * 16 / 256)  // 1024
#define KV_BLOCKS (BB * NN / 256)         // 64

// Round 16: k_attn was per-wave-latency bound (r3: 70us, ~48K cycles/wave for
// ~1.2K instrs = 97% stall; r2<->r3 invariance under 2x waves proves the cost
// is per-wave VMEM latency exposures, not wave count). Also: two-hop mask is
// ~33% dense (1-(1-p1^2)^1024), so sparse lists only win ~3x minus overhead
// -> dense is right; fix memory structure instead.
//  - double-buffered LDS j-tiles: 256 threads cooperatively load tile t+1
//    (one coalesced float4/thread, issued before compute, vmcnt-waited at the
//    LDS write AFTER compute), 4 waves compute tile t from LDS (SoA,
//    conflict-free ds_read_b128). Per-wave exposures 64 -> 16, all hidden.
//  - 16 rows/block (grid BB*64): 4 waves share each tile -> half the global
//    traffic of r3. LDS ~17.7KB (not r1's 63KB occupancy mistake).
//  - tile-0 loads issue at kernel entry, overlapping consts + two-hop phase.
//  Kept: barrier-free two-hop, atomic pool + cntr(63) + last-block MLP,
//  k_pack dtype probe, exp2/log2e folding, no unroll pragma on j-loop.

// ---------------------------------------------------------------- pack + kv
__global__ __launch_bounds__(256) void k_pack(
    const void* __restrict__ adj, const void* __restrict__ feats,
    const void* __restrict__ coors,
    const void* __restrict__ Wk, const void* __restrict__ Wv,
    const void* __restrict__ Wo,
    u64* __restrict__ adjbits, float4* __restrict__ kvg,
    float* __restrict__ czg, int* __restrict__ gflags,
    float* __restrict__ pooled, int* __restrict__ cntr) {
  __shared__ int sNon01, sNonpair, sLow3;
  __shared__ int sCnt[4];
  __shared__ float wkL[25], wvL[25], woL[25];
  int tid = threadIdx.x;

  if (blockIdx.x >= PACK_BLOCKS) {
    // ---------------- kv precompute role ----------------
    int kb = blockIdx.x - PACK_BLOCKS;
    if (kb == 0) {
      // zero pooled accumulators + block counters (workspace is poisoned
      // between iterations); kernel-end flush publishes to k_attn.
      if (tid < BB * DD) pooled[tid] = 0.0f;
      else if (tid < BB * DD + BB) cntr[tid - BB * DD] = 0;
    }
    {
      u32 x = ((const u32*)feats)[tid];
      u32 lo = x & 0xFFFFu;
      int e = (int)((lo >> 7) & 0xFFu);
      bool insane = !(lo == 0u || (e >= 90 && e <= 150));
      u64 m = __ballot(insane);
      if ((tid & 63) == 0) sCnt[tid >> 6] = (int)__popcll(m);
    }
    __syncthreads();
    bool f32 = (sCnt[0] + sCnt[1] + sCnt[2] + sCnt[3]) > 64;
    if (tid < 25) {
      wkL[tid] = ldf(Wk, tid, f32);
      wvL[tid] = ldf(Wv, tid, f32);
      woL[tid] = ldf(Wo, tid, f32);
    }
    if (kb == 0 && tid == 0) gflags[0] = f32 ? 1 : 0;
    __syncthreads();
    long long node = (long long)kb * 256 + tid;  // < BB*NN
    float f0 = ldf(feats, node * DD + 0, f32), f1 = ldf(feats, node * DD + 1, f32),
          f2 = ldf(feats, node * DD + 2, f32), f3 = ldf(feats, node * DD + 3, f32),
          f4 = ldf(feats, node * DD + 4, f32);
    float k[DD], tv[DD], v[DD];
    #pragma unroll
    for (int e = 0; e < DD; ++e) {
      k[e] = f0 * wkL[e] + f1 * wkL[5 + e] + f2 * wkL[10 + e] + f3 * wkL[15 + e] +
             f4 * wkL[20 + e];
      tv[e] = f0 * wvL[e] + f1 * wvL[5 + e] + f2 * wvL[10 + e] + f3 * wvL[15 + e] +
              f4 * wvL[20 + e];
    }
    #pragma unroll
    for (int e = 0; e < DD; ++e)
      v[e] = tv[0] * woL[e] + tv[1] * woL[5 + e] + tv[2] * woL[10 + e] +
             tv[3] * woL[15 + e] + tv[4] * woL[20 + e];
    float cx = ldf(coors, node * 3 + 0, f32);
    float cy = ldf(coors, node * 3 + 1, f32);
    float cz = ldf(coors, node * 3 + 2, f32);
    kvg[node * 3 + 0] = make_float4(k[0], k[1], k[2], k[3]);
    kvg[node * 3 + 1] = make_float4(k[4], v[0], v[1], v[2]);
    kvg[node * 3 + 2] = make_float4(v[3], v[4], cx, cy);
    czg[node] = cz;
    return;
  }

  // ---------------- adjacency pack role ----------------
  if (tid == 0) { sNon01 = 0; sNonpair = 0; sLow3 = 0; }
  __syncthreads();
  {
    const u32* aw = (const u32*)adj;
    int non01 = 0, nonpair = 0, low3 = 0;
    for (int i = tid; i < 4096; i += 256) {
      u32 x = aw[i];
      u32 lo = x & 0xFFFFu, hi = x >> 16;
      non01 |= (x > 1u);
      nonpair |= !((lo == 0u || lo == 0x3F80u) && (hi == 0u || hi == 0x3F80u));
      low3 |= (lo == 0x3F80u);
    }
    if (non01) atomicOr(&sNon01, 1);
    if (nonpair) atomicOr(&sNonpair, 1);
    if (low3) atomicOr(&sLow3, 1);
  }
  __syncthreads();
  // mode: 0=int32, 1=byte, 2=bf16, 3=f32
  int mode;
  if (!sNon01) mode = 0;
  else if (!sNonpair) mode = sLow3 ? 2 : 3;
  else mode = 1;

  int gid = blockIdx.x * 256 + tid;
  int w = gid & 15;
  long long row = gid >> 4;
  long long base = row * NN + (long long)w * 64;
  u64 bits = 0;
  if (mode == 3) {
    const uint4* p = (const uint4*)((const float*)adj + base);
    #pragma unroll
    for (int t = 0; t < 16; ++t) {
      uint4 x = p[t];
      if (x.x << 1) bits |= 1ull << (4 * t + 0);   // ignore -0.0
      if (x.y << 1) bits |= 1ull << (4 * t + 1);
      if (x.z << 1) bits |= 1ull << (4 * t + 2);
      if (x.w << 1) bits |= 1ull << (4 * t + 3);
    }
  } else if (mode == 0) {
    const uint4* p = (const uint4*)((const u32*)adj + base);
    #pragma unroll
    for (int t = 0; t < 16; ++t) {
      uint4 x = p[t];
      if (x.x) bits |= 1ull << (4 * t + 0);
      if (x.y) bits |= 1ull << (4 * t + 1);
      if (x.z) bits |= 1ull << (4 * t + 2);
      if (x.w) bits |= 1ull << (4 * t + 3);
    }
  } else if (mode == 2) {
    const uint4* p = (const uint4*)((const unsigned short*)adj + base);
    #pragma unroll
    for (int t = 0; t < 8; ++t) {
      uint4 x = p[t];
      u32 c[4] = {x.x, x.y, x.z, x.w};
      #pragma unroll
      for (int q = 0; q < 4; ++q) {
        if ((c[q] & 0x7FFFu)) bits |= 1ull << (8 * t + 2 * q + 0);
        if ((c[q] >> 16) & 0x7FFFu) bits |= 1ull << (8 * t + 2 * q + 1);
      }
    }
  } else {
    const uint4* p = (const uint4*)((const unsigned char*)adj + base);
    #pragma unroll
    for (int t = 0; t < 4; ++t) {
      uint4 x = p[t];
      u32 c[4] = {x.x, x.y, x.z, x.w};
      #pragma unroll
      for (int q = 0; q < 4; ++q)
        #pragma unroll
        for (int bb = 0; bb < 4; ++bb)
          if ((c[q] >> (8 * bb)) & 0xFFu) bits |= 1ull << (16 * t + 4 * q + bb);
    }
  }
  adjbits[gid] = bits;
}

// ---------------- fused: two-hop + attention + pool + last-block MLP
__global__ __launch_bounds__(256) void k_attn(
    const void* __restrict__ feats, const void* __restrict__ coors,
    const void* __restrict__ Wq,
    const void* __restrict__ wr1, const void* __restrict__ br1,
    const void* __restrict__ wr2, const void* __restrict__ br2,
    const float4* __restrict__ kvg, const float* __restrict__ czg,
    const int* __restrict__ gflags, const u64* __restrict__ adjbits,
    float* __restrict__ pooled, int* __restrict__ cntr,
    const void* __restrict__ w1, const void* __restrict__ b1,
    const void* __restrict__ w2, const void* __restrict__ b2,
    float* __restrict__ out) {
  __shared__ __align__(16) float4 kvT[2][3][64];  // 6 KB, SoA per buffer
  __shared__ float czT[2][64];                    // 512 B
  __shared__ unsigned short listL[4][NN];         // 8 KB, per-wave partitioned
  __shared__ u64 neighL[16][16];                  // 2 KB, rows per-wave
  __shared__ float qL[16 * DD], ciL[16 * 3];
  __shared__ float wqL[25];
  __shared__ float wrL[3][RH];
  __shared__ float sConst[2];
  __shared__ int sFast, sLast;
  __shared__ float waveC[4][DD];
  __shared__ float pM[DD];
  __shared__ float hL[128];

  int bi = blockIdx.x;
  int b = bi >> 6, chunk = bi & 63;  // 64 chunks of 16 rows, full j range
  int tid = threadIdx.x;

  // issue tile-0 loads immediately: latency overlaps consts + two-hop phase
  const float4* kvb3 = kvg + (size_t)b * NN * 3;
  const float* czb = czg + (size_t)b * NN;
  float4 stg;
  float stgc;
  if (tid < 192) stg = kvb3[tid];
  else stgc = czb[tid - 192];

  bool f32 = gflags[0] != 0;
  if (tid < 25) wqL[tid] = ldf(Wq, tid, f32);
  if (tid >= 64 && tid < 64 + RH) {
    int h = tid - 64;
    wrL[0][h] = ldf(wr1, h, f32);
    wrL[1][h] = ldf(br1, h, f32);
    wrL[2][h] = ldf(wr2, h, f32);
  }
  if (tid == 96) {
    float c = 0.0f;
    int ok = 1;
    #pragma unroll
    for (int h = 0; h < RH; ++h) {
      float w1h = ldf(wr1, h, f32);
      if (ldf(br1, h, f32) != 0.0f) ok = 0;
      if (w1h > 0.0f) c += w1h * ldf(wr2, h, f32);
    }
    sConst[0] = c * LOG2E;
    sConst[1] = ldf(br2, 0, f32) * LOG2E;
    sFast = ok;
  }
  __syncthreads();
  int fast = sFast;
  // q (scaled) + ci for this chunk's 16 rows
  if (tid < 16) {
    long long row = (long long)b * NN + chunk * 16 + tid;
    float f0 = ldf(feats, row * DD + 0, f32), f1 = ldf(feats, row * DD + 1, f32),
          f2 = ldf(feats, row * DD + 2, f32), f3 = ldf(feats, row * DD + 3, f32),
          f4 = ldf(feats, row * DD + 4, f32);
    float qsc = fast ? (0.4472135954999579f * LOG2E) : 0.4472135954999579f;
    #pragma unroll
    for (int e = 0; e < DD; ++e)
      qL[tid * DD + e] = (f0 * wqL[e] + f1 * wqL[5 + e] + f2 * wqL[10 + e] +
                          f3 * wqL[15 + e] + f4 * wqL[20 + e]) * qsc;
    #pragma unroll
    for (int c = 0; c < 3; ++c)
      ciL[tid * 3 + c] = ldf(coors, row * 3 + c, f32);
  }

  // ---- two-hop masks, barrier-free (per-wave lists and rows, 4 rows/wave)
  int g = tid >> 6, lane = tid & 63;
  int w = lane & 15, grp = lane >> 4;
  const u64* basep = adjbits + (size_t)b * NN * 16;
  for (int rr = 0; rr < 4; ++rr) {
    int il = g * 4 + rr;            // local row 0..15, owned by wave g
    int i = chunk * 16 + il;        // batch row
    u64 rw = basep[(size_t)i * 16 + w];
    unsigned short* list = listL[g];
    int cnt = 0;
    #pragma unroll
    for (int sw = 0; sw < 16; ++sw) {
      u64 bits = __shfl(rw, sw, 64);
      int mybit = (int)((bits >> lane) & 1ull);
      int pre = __popcll(bits & ((1ull << lane) - 1ull));
      if (mybit) list[cnt + pre] = (unsigned short)(sw * 64 + lane);
      cnt += __popcll(bits);
    }
    u64 acc = rw;
    if (w == (i >> 6)) acc |= 1ull << (i & 63);
    for (int n = grp; n < cnt; n += 4) acc |= basep[(size_t)list[n] * 16 + w];
    acc |= __shfl_xor(acc, 16, 64);
    acc |= __shfl_xor(acc, 32, 64);
    if (lane < 16) neighL[il][lane] = acc;
  }

  // write tile 0 into buf 0 (waits on the entry loads)
  if (tid < 192) kvT[0][tid % 3][tid / 3] = stg;
  else czT[0][tid - 192] = stgc;
  __syncthreads();  // buf0 ready; qL/ciL/sConst visible to all waves

  // ---- attention over full j range, double-buffered LDS tiles
  float q[4][DD], ci[4][3], l[4], A[4][DD];
  #pragma unroll
  for (int r = 0; r < 4; ++r) {
    #pragma unroll
    for (int e = 0; e < DD; ++e) q[r][e] = qL[(g * 4 + r) * DD + e];
    #pragma unroll
    for (int c = 0; c < 3; ++c) ci[r][c] = ciL[(g * 4 + r) * 3 + c];
    l[r] = 0.0f;
    #pragma unroll
    for (int e = 0; e < DD; ++e) A[r][e] = 0.0f;
  }
  float Cf = sConst[0], br2f = sConst[1];
  int cur = 0;
  for (int t = 0; t < 16; ++t) {
    // issue next tile's coalesced loads (wait deferred to the LDS write)
    if (t < 15) {
      if (tid < 192) stg = kvb3[(size_t)(t + 1) * 192 + tid];
      else stgc = czb[(t + 1) * 64 + (tid - 192)];
    }
    float4 ka = kvT[cur][0][lane];
    float4 kb = kvT[cur][1][lane];
    float4 kc = kvT[cur][2][lane];
    float jz = czT[cur][lane];
    float jx = kc.z, jy = kc.w;
    u64 nw[4];
    #pragma unroll
    for (int r = 0; r < 4; ++r) nw[r] = neighL[g * 4 + r][t];
    if (fast) {
      #pragma unroll
      for (int r = 0; r < 4; ++r) {
        float cx = jx - ci[r][0], cy = jy - ci[r][1], cz = jz - ci[r][2];
        float dist =
            __builtin_amdgcn_sqrtf(fmaf(cx, cx, fmaf(cy, cy, fmaf(cz, cz, 1e-8f))));
        float s = fmaf(q[r][0], ka.x, br2f);
        s = fmaf(q[r][1], ka.y, s);
        s = fmaf(q[r][2], ka.z, s);
        s = fmaf(q[r][3], ka.w, s);
        s = fmaf(q[r][4], kb.x, s);
        s = fmaf(Cf, dist, s);
        s = fminf(s, 126.0f);
        s = ((nw[r] >> lane) & 1ull) ? s : -150.0f;
        float p = __builtin_amdgcn_exp2f(s);
        l[r] += p;
        A[r][0] = fmaf(p, kb.y, A[r][0]);
        A[r][1] = fmaf(p, kb.z, A[r][1]);
        A[r][2] = fmaf(p, kb.w, A[r][2]);
        A[r][3] = fmaf(p, kc.x, A[r][3]);
        A[r][4] = fmaf(p, kc.y, A[r][4]);
      }
    } else {
      #pragma unroll
      for (int r = 0; r < 4; ++r) {
        float cx = jx - ci[r][0], cy = jy - ci[r][1], cz = jz - ci[r][2];
        float dist = sqrtf(fmaf(cx, cx, fmaf(cy, cy, fmaf(cz, cz, 1e-8f))));
        float rb = ldf(br2, 0, f32);
        #pragma unroll
        for (int h = 0; h < RH; ++h)
          rb += fmaxf(dist * wrL[0][h] + wrL[1][h], 0.0f) * wrL[2][h];
        float s = fmaf(q[r][0], ka.x, rb);
        s = fmaf(q[r][1], ka.y, s);
        s = fmaf(q[r][2], ka.z, s);
        s = fmaf(q[r][3], ka.w, s);
        s = fmaf(q[r][4], kb.x, s);
        s = fminf(s, 85.0f);
        s = ((nw[r] >> lane) & 1ull) ? s : -100.0f;
        float p = __expf(s);
        l[r] += p;
        A[r][0] = fmaf(p, kb.y, A[r][0]);
        A[r][1] = fmaf(p, kb.z, A[r][1]);
        A[r][2] = fmaf(p, kb.w, A[r][2]);
        A[r][3] = fmaf(p, kc.x, A[r][3]);
        A[r][4] = fmaf(p, kc.y, A[r][4]);
      }
    }
    // land next tile into the other buffer; current readers untouched
    if (t < 15) {
      if (tid < 192) kvT[cur ^ 1][tid % 3][tid / 3] = stg;
      else czT[cur ^ 1][tid - 192] = stgc;
    }
    __syncthreads();
    cur ^= 1;
  }
  #pragma unroll
  for (int msk = 1; msk < 64; msk <<= 1) {
    #pragma unroll
    for (int r = 0; r < 4; ++r) {
      l[r] += __shfl_xor(l[r], msk, 64);
      A[r][0] += __shfl_xor(A[r][0], msk, 64);
      A[r][1] += __shfl_xor(A[r][1], msk, 64);
      A[r][2] += __shfl_xor(A[r][2], msk, 64);
      A[r][3] += __shfl_xor(A[r][3], msk, 64);
      A[r][4] += __shfl_xor(A[r][4], msk, 64);
    }
  }

  // ---- per-row contribution (denominator complete) -> block-partial pool
  if (lane == 0) {
    float cw[DD] = {0.f, 0.f, 0.f, 0.f, 0.f};
    #pragma unroll
    for (int r = 0; r < 4; ++r) {
      long long grow = (long long)b * NN + chunk * 16 + g * 4 + r;
      float inv = (l[r] > 0.0f) ? 1.0f / l[r] : 0.0f;
      #pragma unroll
      for (int e = 0; e < DD; ++e)
        cw[e] += ldf(feats, grow * DD + e, f32) + A[r][e] * inv;
    }
    #pragma unroll
    for (int e = 0; e < DD; ++e) waveC[g][e] = cw[e];
  }
  __syncthreads();
  if (tid < DD) {
    float s = waveC[0][tid] + waveC[1][tid] + waveC[2][tid] + waveC[3][tid];
    float old = atomicAdd(&pooled[b * DD + tid], s);  // device-scope, coherent
    asm volatile("" :: "v"(old));  // consume return -> add completed before cnt
  }
  __syncthreads();  // vmcnt drain: all 5 pooled adds done before counter bump
  if (tid == 0) sLast = (atomicAdd(&cntr[b], 1) == 63) ? 1 : 0;
  __syncthreads();

  // ---- last block for this b runs the pooled MLP
  if (sLast) {
    if (tid < DD) {
      // agent-scope load: bypass potentially-stale local L2
      float pv = __hip_atomic_load(&pooled[b * DD + tid], __ATOMIC_RELAXED,
                                   __HIP_MEMORY_SCOPE_AGENT);
      pM[tid] = pv * (1.0f / 1024.0f);
    }
    __syncthreads();
    if (tid < 128) {
      float acc = ldf(b1, tid, f32);
      #pragma unroll
      for (int d = 0; d < DD; ++d)
        acc = fmaf(pM[d], ldf(w1, d * 128 + tid, f32), acc);
      hL[tid] = fmaxf(acc, 0.0f);
    }
    __syncthreads();
    if (tid < 3) {
      float s = ldf(b2, tid, f32);
      for (int j2 = 0; j2 < 128; ++j2)
        s = fmaf(hL[j2], ldf(w2, j2 * 3 + tid, f32), s);
      out[b * 3 + tid] = s;
    }
  }
}

// ---------------------------------------------------------------- launch
extern "C" void kernel_launch(void* const* d_in, const int* in_sizes, int n_in,
                              void* d_out, int out_size, void* d_ws, size_t ws_size,
                              hipStream_t stream) {
  const void* adj = d_in[2];
  float* out = (float*)d_out;

  char* w = (char*)d_ws;
  int* gflags = (int*)w;                               // 16 B
  float* pooled = (float*)(w + 64);                    // 320 B
  int* cntr = (int*)(w + 512);                         // 64 B
  const size_t MB2 = (size_t)BB * NN * 16 * sizeof(u64);  // 2 MiB
  u64* adjbits = (u64*)(w + 1024);
  float4* kvg = (float4*)(w + 1024 + MB2);             // 768 KiB
  float* czg = (float*)(w + 1024 + MB2 + 786432);      // 64 KiB

  k_pack<<<PACK_BLOCKS + KV_BLOCKS, 256, 0, stream>>>(
      adj, d_in[0], d_in[1], d_in[4], d_in[5], d_in[6], adjbits, kvg, czg,
      gflags, pooled, cntr);
  k_attn<<<BB * 64, 256, 0, stream>>>(
      d_in[0], d_in[1], d_in[3], d_in[7], d_in[8], d_in[9], d_in[10], kvg, czg,
      gflags, adjbits, pooled, cntr, d_in[11], d_in[12], d_in[13], d_in[14],
      out);
}

// Round 5
// 187.157 us; speedup vs baseline: 1.0803x; 1.0165x over previous
//
#include <hip/hip_runtime.h>
#include <hip/hip_bf16.h>

#define BB 16
#define NN 1024
#define DD 5
#define RH 8

typedef unsigned long long u64;
typedef unsigned int u32;
typedef __hip_bfloat16 bf16;

static __device__ __forceinline__ float tof(bf16 x) { return __bfloat162float(x); }
// runtime-dtype load: f32 storage if f==true else bf16
static __device__ __forceinline__ float ldf(const void* p, long long i, bool f) {
  return f ? ((const float*)p)[i] : tof(((const bf16*)p)[i]);
}

#define LOG2E 1.4426950408889634f
#define PACK_BLOCKS (BB * NN * 16 / 256)  // 1024
#define KV_BLOCKS (BB * NN / 256)         // 64

// Round 17: r2/r3/r4 all ~69-70us under three different memory structures ->
// limiter is exposed dependent-chain latency through a THIN wave population.
// r3 had waves without the pipeline; r4 had the pipeline without waves
// (1024x4 = 16 waves/CU = 50% cap, measured 19%). This round: both.
//  - 512-thread blocks (8 waves, 2 rows/wave), grid stays 1024:
//    8192 waves = 8/SIMD = 100% occupancy headroom; 2-row body measured
//    VGPR=60 in r3 (<=64 keeps 8 waves/SIMD allocatable).
//  - keep r4's double-buffered LDS kv tiles (per-wave VMEM exposures stay
//    hidden), fused two-hop, atomic pool + cntr + last-block MLP.
//  Pre-committed read: occ up >=2x but dur ~69 -> falsifies occupancy theory,
//  next step is j-split partial softmax (r12 shape).

// ---------------------------------------------------------------- pack + kv
__global__ __launch_bounds__(256) void k_pack(
    const void* __restrict__ adj, const void* __restrict__ feats,
    const void* __restrict__ coors,
    const void* __restrict__ Wk, const void* __restrict__ Wv,
    const void* __restrict__ Wo,
    u64* __restrict__ adjbits, float4* __restrict__ kvg,
    float* __restrict__ czg, int* __restrict__ gflags,
    float* __restrict__ pooled, int* __restrict__ cntr) {
  __shared__ int sNon01, sNonpair, sLow3;
  __shared__ int sCnt[4];
  __shared__ float wkL[25], wvL[25], woL[25];
  int tid = threadIdx.x;

  if (blockIdx.x >= PACK_BLOCKS) {
    // ---------------- kv precompute role ----------------
    int kb = blockIdx.x - PACK_BLOCKS;
    if (kb == 0) {
      // zero pooled accumulators + block counters (workspace is poisoned
      // between iterations); kernel-end flush publishes to k_attn.
      if (tid < BB * DD) pooled[tid] = 0.0f;
      else if (tid < BB * DD + BB) cntr[tid - BB * DD] = 0;
    }
    {
      u32 x = ((const u32*)feats)[tid];
      u32 lo = x & 0xFFFFu;
      int e = (int)((lo >> 7) & 0xFFu);
      bool insane = !(lo == 0u || (e >= 90 && e <= 150));
      u64 m = __ballot(insane);
      if ((tid & 63) == 0) sCnt[tid >> 6] = (int)__popcll(m);
    }
    __syncthreads();
    bool f32 = (sCnt[0] + sCnt[1] + sCnt[2] + sCnt[3]) > 64;
    if (tid < 25) {
      wkL[tid] = ldf(Wk, tid, f32);
      wvL[tid] = ldf(Wv, tid, f32);
      woL[tid] = ldf(Wo, tid, f32);
    }
    if (kb == 0 && tid == 0) gflags[0] = f32 ? 1 : 0;
    __syncthreads();
    long long node = (long long)kb * 256 + tid;  // < BB*NN
    float f0 = ldf(feats, node * DD + 0, f32), f1 = ldf(feats, node * DD + 1, f32),
          f2 = ldf(feats, node * DD + 2, f32), f3 = ldf(feats, node * DD + 3, f32),
          f4 = ldf(feats, node * DD + 4, f32);
    float k[DD], tv[DD], v[DD];
    #pragma unroll
    for (int e = 0; e < DD; ++e) {
      k[e] = f0 * wkL[e] + f1 * wkL[5 + e] + f2 * wkL[10 + e] + f3 * wkL[15 + e] +
             f4 * wkL[20 + e];
      tv[e] = f0 * wvL[e] + f1 * wvL[5 + e] + f2 * wvL[10 + e] + f3 * wvL[15 + e] +
              f4 * wvL[20 + e];
    }
    #pragma unroll
    for (int e = 0; e < DD; ++e)
      v[e] = tv[0] * woL[e] + tv[1] * woL[5 + e] + tv[2] * woL[10 + e] +
             tv[3] * woL[15 + e] + tv[4] * woL[20 + e];
    float cx = ldf(coors, node * 3 + 0, f32);
    float cy = ldf(coors, node * 3 + 1, f32);
    float cz = ldf(coors, node * 3 + 2, f32);
    kvg[node * 3 + 0] = make_float4(k[0], k[1], k[2], k[3]);
    kvg[node * 3 + 1] = make_float4(k[4], v[0], v[1], v[2]);
    kvg[node * 3 + 2] = make_float4(v[3], v[4], cx, cy);
    czg[node] = cz;
    return;
  }

  // ---------------- adjacency pack role ----------------
  if (tid == 0) { sNon01 = 0; sNonpair = 0; sLow3 = 0; }
  __syncthreads();
  {
    const u32* aw = (const u32*)adj;
    int non01 = 0, nonpair = 0, low3 = 0;
    for (int i = tid; i < 4096; i += 256) {
      u32 x = aw[i];
      u32 lo = x & 0xFFFFu, hi = x >> 16;
      non01 |= (x > 1u);
      nonpair |= !((lo == 0u || lo == 0x3F80u) && (hi == 0u || hi == 0x3F80u));
      low3 |= (lo == 0x3F80u);
    }
    if (non01) atomicOr(&sNon01, 1);
    if (nonpair) atomicOr(&sNonpair, 1);
    if (low3) atomicOr(&sLow3, 1);
  }
  __syncthreads();
  // mode: 0=int32, 1=byte, 2=bf16, 3=f32
  int mode;
  if (!sNon01) mode = 0;
  else if (!sNonpair) mode = sLow3 ? 2 : 3;
  else mode = 1;

  int gid = blockIdx.x * 256 + tid;
  int w = gid & 15;
  long long row = gid >> 4;
  long long base = row * NN + (long long)w * 64;
  u64 bits = 0;
  if (mode == 3) {
    const uint4* p = (const uint4*)((const float*)adj + base);
    #pragma unroll
    for (int t = 0; t < 16; ++t) {
      uint4 x = p[t];
      if (x.x << 1) bits |= 1ull << (4 * t + 0);   // ignore -0.0
      if (x.y << 1) bits |= 1ull << (4 * t + 1);
      if (x.z << 1) bits |= 1ull << (4 * t + 2);
      if (x.w << 1) bits |= 1ull << (4 * t + 3);
    }
  } else if (mode == 0) {
    const uint4* p = (const uint4*)((const u32*)adj + base);
    #pragma unroll
    for (int t = 0; t < 16; ++t) {
      uint4 x = p[t];
      if (x.x) bits |= 1ull << (4 * t + 0);
      if (x.y) bits |= 1ull << (4 * t + 1);
      if (x.z) bits |= 1ull << (4 * t + 2);
      if (x.w) bits |= 1ull << (4 * t + 3);
    }
  } else if (mode == 2) {
    const uint4* p = (const uint4*)((const unsigned short*)adj + base);
    #pragma unroll
    for (int t = 0; t < 8; ++t) {
      uint4 x = p[t];
      u32 c[4] = {x.x, x.y, x.z, x.w};
      #pragma unroll
      for (int q = 0; q < 4; ++q) {
        if ((c[q] & 0x7FFFu)) bits |= 1ull << (8 * t + 2 * q + 0);
        if ((c[q] >> 16) & 0x7FFFu) bits |= 1ull << (8 * t + 2 * q + 1);
      }
    }
  } else {
    const uint4* p = (const uint4*)((const unsigned char*)adj + base);
    #pragma unroll
    for (int t = 0; t < 4; ++t) {
      uint4 x = p[t];
      u32 c[4] = {x.x, x.y, x.z, x.w};
      #pragma unroll
      for (int q = 0; q < 4; ++q)
        #pragma unroll
        for (int bb = 0; bb < 4; ++bb)
          if ((c[q] >> (8 * bb)) & 0xFFu) bits |= 1ull << (16 * t + 4 * q + bb);
    }
  }
  adjbits[gid] = bits;
}

// ---------------- fused: two-hop + attention + pool + last-block MLP
__global__ __launch_bounds__(512) void k_attn(
    const void* __restrict__ feats, const void* __restrict__ coors,
    const void* __restrict__ Wq,
    const void* __restrict__ wr1, const void* __restrict__ br1,
    const void* __restrict__ wr2, const void* __restrict__ br2,
    const float4* __restrict__ kvg, const float* __restrict__ czg,
    const int* __restrict__ gflags, const u64* __restrict__ adjbits,
    float* __restrict__ pooled, int* __restrict__ cntr,
    const void* __restrict__ w1, const void* __restrict__ b1,
    const void* __restrict__ w2, const void* __restrict__ b2,
    float* __restrict__ out) {
  __shared__ __align__(16) float4 kvT[2][3][64];  // 6 KB, SoA per buffer
  __shared__ float czT[2][64];                    // 512 B
  __shared__ unsigned short listL[8][NN];         // 16 KB, per-wave partitioned
  __shared__ u64 neighL[16][16];                  // 2 KB, rows per-wave-pair
  __shared__ float qL[16 * DD], ciL[16 * 3];
  __shared__ float wqL[25];
  __shared__ float wrL[3][RH];
  __shared__ float sConst[2];
  __shared__ int sFast, sLast;
  __shared__ float waveC[8][DD];
  __shared__ float pM[DD];
  __shared__ float hL[128];

  int bi = blockIdx.x;
  int b = bi >> 6, chunk = bi & 63;  // 64 chunks of 16 rows, full j range
  int tid = threadIdx.x;

  // issue tile-0 loads immediately: latency overlaps consts + two-hop phase
  const float4* kvb3 = kvg + (size_t)b * NN * 3;
  const float* czb = czg + (size_t)b * NN;
  bool ldkv = tid < 192;
  bool ldcz = (tid >= 192) && (tid < 256);
  float4 stg;
  float stgc;
  if (ldkv) stg = kvb3[tid];
  else if (ldcz) stgc = czb[tid - 192];

  bool f32 = gflags[0] != 0;
  if (tid < 25) wqL[tid] = ldf(Wq, tid, f32);
  if (tid >= 64 && tid < 64 + RH) {
    int h = tid - 64;
    wrL[0][h] = ldf(wr1, h, f32);
    wrL[1][h] = ldf(br1, h, f32);
    wrL[2][h] = ldf(wr2, h, f32);
  }
  if (tid == 96) {
    float c = 0.0f;
    int ok = 1;
    #pragma unroll
    for (int h = 0; h < RH; ++h) {
      float w1h = ldf(wr1, h, f32);
      if (ldf(br1, h, f32) != 0.0f) ok = 0;
      if (w1h > 0.0f) c += w1h * ldf(wr2, h, f32);
    }
    sConst[0] = c * LOG2E;
    sConst[1] = ldf(br2, 0, f32) * LOG2E;
    sFast = ok;
  }
  __syncthreads();
  int fast = sFast;
  // q (scaled) + ci for this chunk's 16 rows
  if (tid < 16) {
    long long row = (long long)b * NN + chunk * 16 + tid;
    float f0 = ldf(feats, row * DD + 0, f32), f1 = ldf(feats, row * DD + 1, f32),
          f2 = ldf(feats, row * DD + 2, f32), f3 = ldf(feats, row * DD + 3, f32),
          f4 = ldf(feats, row * DD + 4, f32);
    float qsc = fast ? (0.4472135954999579f * LOG2E) : 0.4472135954999579f;
    #pragma unroll
    for (int e = 0; e < DD; ++e)
      qL[tid * DD + e] = (f0 * wqL[e] + f1 * wqL[5 + e] + f2 * wqL[10 + e] +
                          f3 * wqL[15 + e] + f4 * wqL[20 + e]) * qsc;
    #pragma unroll
    for (int c = 0; c < 3; ++c)
      ciL[tid * 3 + c] = ldf(coors, row * 3 + c, f32);
  }

  // ---- two-hop masks, barrier-free (per-wave lists, 2 rows/wave)
  int g = tid >> 6, lane = tid & 63;
  int w = lane & 15, grp = lane >> 4;
  const u64* basep = adjbits + (size_t)b * NN * 16;
  for (int rr = 0; rr < 2; ++rr) {
    int il = g * 2 + rr;            // local row 0..15, owned by wave g
    int i = chunk * 16 + il;        // batch row
    u64 rw = basep[(size_t)i * 16 + w];
    unsigned short* list = listL[g];
    int cnt = 0;
    #pragma unroll
    for (int sw = 0; sw < 16; ++sw) {
      u64 bits = __shfl(rw, sw, 64);
      int mybit = (int)((bits >> lane) & 1ull);
      int pre = __popcll(bits & ((1ull << lane) - 1ull));
      if (mybit) list[cnt + pre] = (unsigned short)(sw * 64 + lane);
      cnt += __popcll(bits);
    }
    u64 acc = rw;
    if (w == (i >> 6)) acc |= 1ull << (i & 63);
    for (int n = grp; n < cnt; n += 4) acc |= basep[(size_t)list[n] * 16 + w];
    acc |= __shfl_xor(acc, 16, 64);
    acc |= __shfl_xor(acc, 32, 64);
    if (lane < 16) neighL[il][lane] = acc;
  }

  // write tile 0 into buf 0 (waits on the entry loads)
  if (ldkv) kvT[0][tid % 3][tid / 3] = stg;
  else if (ldcz) czT[0][tid - 192] = stgc;
  __syncthreads();  // buf0 ready; qL/ciL/sConst visible to all waves

  // ---- attention over full j range, double-buffered LDS tiles
  float q[2][DD], ci[2][3], l[2], A[2][DD];
  #pragma unroll
  for (int r = 0; r < 2; ++r) {
    #pragma unroll
    for (int e = 0; e < DD; ++e) q[r][e] = qL[(g * 2 + r) * DD + e];
    #pragma unroll
    for (int c = 0; c < 3; ++c) ci[r][c] = ciL[(g * 2 + r) * 3 + c];
    l[r] = 0.0f;
    #pragma unroll
    for (int e = 0; e < DD; ++e) A[r][e] = 0.0f;
  }
  float Cf = sConst[0], br2f = sConst[1];
  int cur = 0;
  for (int t = 0; t < 16; ++t) {
    // issue next tile's coalesced loads (wait deferred to the LDS write)
    if (t < 15) {
      if (ldkv) stg = kvb3[(size_t)(t + 1) * 192 + tid];
      else if (ldcz) stgc = czb[(t + 1) * 64 + (tid - 192)];
    }
    float4 ka = kvT[cur][0][lane];
    float4 kb = kvT[cur][1][lane];
    float4 kc = kvT[cur][2][lane];
    float jz = czT[cur][lane];
    float jx = kc.z, jy = kc.w;
    u64 nw[2];
    #pragma unroll
    for (int r = 0; r < 2; ++r) nw[r] = neighL[g * 2 + r][t];
    if (fast) {
      #pragma unroll
      for (int r = 0; r < 2; ++r) {
        float cx = jx - ci[r][0], cy = jy - ci[r][1], cz = jz - ci[r][2];
        float dist =
            __builtin_amdgcn_sqrtf(fmaf(cx, cx, fmaf(cy, cy, fmaf(cz, cz, 1e-8f))));
        float s = fmaf(q[r][0], ka.x, br2f);
        s = fmaf(q[r][1], ka.y, s);
        s = fmaf(q[r][2], ka.z, s);
        s = fmaf(q[r][3], ka.w, s);
        s = fmaf(q[r][4], kb.x, s);
        s = fmaf(Cf, dist, s);
        s = fminf(s, 126.0f);
        s = ((nw[r] >> lane) & 1ull) ? s : -150.0f;
        float p = __builtin_amdgcn_exp2f(s);
        l[r] += p;
        A[r][0] = fmaf(p, kb.y, A[r][0]);
        A[r][1] = fmaf(p, kb.z, A[r][1]);
        A[r][2] = fmaf(p, kb.w, A[r][2]);
        A[r][3] = fmaf(p, kc.x, A[r][3]);
        A[r][4] = fmaf(p, kc.y, A[r][4]);
      }
    } else {
      #pragma unroll
      for (int r = 0; r < 2; ++r) {
        float cx = jx - ci[r][0], cy = jy - ci[r][1], cz = jz - ci[r][2];
        float dist = sqrtf(fmaf(cx, cx, fmaf(cy, cy, fmaf(cz, cz, 1e-8f))));
        float rb = ldf(br2, 0, f32);
        #pragma unroll
        for (int h = 0; h < RH; ++h)
          rb += fmaxf(dist * wrL[0][h] + wrL[1][h], 0.0f) * wrL[2][h];
        float s = fmaf(q[r][0], ka.x, rb);
        s = fmaf(q[r][1], ka.y, s);
        s = fmaf(q[r][2], ka.z, s);
        s = fmaf(q[r][3], ka.w, s);
        s = fmaf(q[r][4], kb.x, s);
        s = fminf(s, 85.0f);
        s = ((nw[r] >> lane) & 1ull) ? s : -100.0f;
        float p = __expf(s);
        l[r] += p;
        A[r][0] = fmaf(p, kb.y, A[r][0]);
        A[r][1] = fmaf(p, kb.z, A[r][1]);
        A[r][2] = fmaf(p, kb.w, A[r][2]);
        A[r][3] = fmaf(p, kc.x, A[r][3]);
        A[r][4] = fmaf(p, kc.y, A[r][4]);
      }
    }
    // land next tile into the other buffer; current readers untouched
    if (t < 15) {
      if (ldkv) kvT[cur ^ 1][tid % 3][tid / 3] = stg;
      else if (ldcz) czT[cur ^ 1][tid - 192] = stgc;
    }
    __syncthreads();
    cur ^= 1;
  }
  #pragma unroll
  for (int msk = 1; msk < 64; msk <<= 1) {
    #pragma unroll
    for (int r = 0; r < 2; ++r) {
      l[r] += __shfl_xor(l[r], msk, 64);
      A[r][0] += __shfl_xor(A[r][0], msk, 64);
      A[r][1] += __shfl_xor(A[r][1], msk, 64);
      A[r][2] += __shfl_xor(A[r][2], msk, 64);
      A[r][3] += __shfl_xor(A[r][3], msk, 64);
      A[r][4] += __shfl_xor(A[r][4], msk, 64);
    }
  }

  // ---- per-row contribution (denominator complete) -> block-partial pool
  if (lane == 0) {
    float cw[DD] = {0.f, 0.f, 0.f, 0.f, 0.f};
    #pragma unroll
    for (int r = 0; r < 2; ++r) {
      long long grow = (long long)b * NN + chunk * 16 + g * 2 + r;
      float inv = (l[r] > 0.0f) ? 1.0f / l[r] : 0.0f;
      #pragma unroll
      for (int e = 0; e < DD; ++e)
        cw[e] += ldf(feats, grow * DD + e, f32) + A[r][e] * inv;
    }
    #pragma unroll
    for (int e = 0; e < DD; ++e) waveC[g][e] = cw[e];
  }
  __syncthreads();
  if (tid < DD) {
    float s = waveC[0][tid] + waveC[1][tid] + waveC[2][tid] + waveC[3][tid] +
              waveC[4][tid] + waveC[5][tid] + waveC[6][tid] + waveC[7][tid];
    float old = atomicAdd(&pooled[b * DD + tid], s);  // device-scope, coherent
    asm volatile("" :: "v"(old));  // consume return -> add completed before cnt
  }
  __syncthreads();  // vmcnt drain: all 5 pooled adds done before counter bump
  if (tid == 0) sLast = (atomicAdd(&cntr[b], 1) == 63) ? 1 : 0;
  __syncthreads();

  // ---- last block for this b runs the pooled MLP
  if (sLast) {
    if (tid < DD) {
      // agent-scope load: bypass potentially-stale local L2
      float pv = __hip_atomic_load(&pooled[b * DD + tid], __ATOMIC_RELAXED,
                                   __HIP_MEMORY_SCOPE_AGENT);
      pM[tid] = pv * (1.0f / 1024.0f);
    }
    __syncthreads();
    if (tid < 128) {
      float acc = ldf(b1, tid, f32);
      #pragma unroll
      for (int d = 0; d < DD; ++d)
        acc = fmaf(pM[d], ldf(w1, d * 128 + tid, f32), acc);
      hL[tid] = fmaxf(acc, 0.0f);
    }
    __syncthreads();
    if (tid < 3) {
      float s = ldf(b2, tid, f32);
      for (int j2 = 0; j2 < 128; ++j2)
        s = fmaf(hL[j2], ldf(w2, j2 * 3 + tid, f32), s);
      out[b * 3 + tid] = s;
    }
  }
}

// ---------------------------------------------------------------- launch
extern "C" void kernel_launch(void* const* d_in, const int* in_sizes, int n_in,
                              void* d_out, int out_size, void* d_ws, size_t ws_size,
                              hipStream_t stream) {
  const void* adj = d_in[2];
  float* out = (float*)d_out;

  char* w = (char*)d_ws;
  int* gflags = (int*)w;                               // 16 B
  float* pooled = (float*)(w + 64);                    // 320 B
  int* cntr = (int*)(w + 512);                         // 64 B
  const size_t MB2 = (size_t)BB * NN * 16 * sizeof(u64);  // 2 MiB
  u64* adjbits = (u64*)(w + 1024);
  float4* kvg = (float4*)(w + 1024 + MB2);             // 768 KiB
  float* czg = (float*)(w + 1024 + MB2 + 786432);      // 64 KiB

  k_pack<<<PACK_BLOCKS + KV_BLOCKS, 256, 0, stream>>>(
      adj, d_in[0], d_in[1], d_in[4], d_in[5], d_in[6], adjbits, kvg, czg,
      gflags, pooled, cntr);
  k_attn<<<BB * 64, 512, 0, stream>>>(
      d_in[0], d_in[1], d_in[3], d_in[7], d_in[8], d_in[9], d_in[10], kvg, czg,
      gflags, adjbits, pooled, cntr, d_in[11], d_in[12], d_in[13], d_in[14],
      out);
}